// Round 10
// baseline (151.774 us; speedup 1.0000x reference)
//
#include <hip/hip_runtime.h>
#include <hip/hip_bf16.h>

typedef __attribute__((ext_vector_type(8))) short bf16x8;
typedef __attribute__((ext_vector_type(4))) float f32x4;

__device__ __forceinline__ ushort f2bf(float f) {
    __hip_bfloat16 h = __float2bfloat16(f);
    return __builtin_bit_cast(ushort, h);
}
__device__ __forceinline__ float bflo(unsigned u) { return __uint_as_float(u << 16); }
__device__ __forceinline__ float bfhi(unsigned u) { return __uint_as_float(u & 0xffff0000u); }

__device__ __forceinline__ void unpack8(uint4 r, float* o) {
    o[0] = bflo(r.x); o[1] = bfhi(r.x); o[2] = bflo(r.y); o[3] = bfhi(r.y);
    o[4] = bflo(r.z); o[5] = bfhi(r.z); o[6] = bflo(r.w); o[7] = bfhi(r.w);
}

// ---------------------------------------------------------------------------
// L1: convert w_kv to bf16 AND zero atomic accumulators
__global__ void cvtw_kernel(const float* __restrict__ w, ushort* __restrict__ o,
                            float* __restrict__ zbase) {
    int i = blockIdx.x * 256 + threadIdx.x;      // 0..131071
    if (i < 68608) zbase[i] = 0.f;
    o[i] = f2bf(w[i]);
}

// ---------------------------------------------------------------------------
// L2 merged: blocks [0,1024): kv = w_kv @ cond (64x64 MFMA tiles); A and B
//   reg-staged with next-tile prefetch (no global_load_lds -> no vmcnt drains).
//   blocks [1024,3072): GroupNorm sums for x, one block per (b,g)-quarter.
__global__ __launch_bounds__(256) void kvstats_kernel(const ushort* __restrict__ wkv16,
                                                      const float* __restrict__ cond,
                                                      const float* __restrict__ b_kv,
                                                      ushort* __restrict__ kv16,
                                                      const float* __restrict__ x,
                                                      float* __restrict__ statacc) {
    __shared__ ushort lA[64 * 64];      // 8 KB
    __shared__ ushort lB[64 * 64];      // 8 KB
    __shared__ float scratch[64 * 64];  // 16 KB, granule-swizzled
    __shared__ float red[8];
    int bid = blockIdx.x;
    int t = threadIdx.x;
    if (bid < 1024) {
        int nb = bid & 15, ob = (bid >> 4) & 3, b = bid >> 6;
        int col0 = nb * 64, row0 = ob * 64;
        int l = t & 63, wid = t >> 6;
        int wr = wid >> 1, wc = wid & 1;
        int lr = l & 15, lg = l >> 4;
        const ushort* Ab = wkv16 + (size_t)row0 * 512;
        const float* Bb = cond + (size_t)b * 512 * 1024 + col0;
        int sp = t & 31, sj = t >> 5;   // c-pair (2sp,2sp+1), n-octet sj*8
        uint4 aR[2]; float4 bR[4];
        auto LOADA = [&](int k0) {
            #pragma unroll
            for (int j = 0; j < 2; ++j) {
                int gi = j * 256 + t, r = gi >> 3, g = (gi & 7) ^ (r & 7);
                aR[j] = *(const uint4*)(Ab + (size_t)r * 512 + k0 + g * 8);
            }
        };
        auto LOADB = [&](int k0) {
            #pragma unroll
            for (int j = 0; j < 4; ++j) {
                int s = j * 256 + t, r = s >> 4, g = s & 15;
                bR[j] = *(const float4*)&Bb[(size_t)(k0 + r) * 1024 + g * 4];
            }
        };
        LOADA(0); LOADB(0);
        f32x4 acc[2][2] = {};
        for (int it = 0; it < 8; ++it) {
            // write staged regs -> LDS
            #pragma unroll
            for (int j = 0; j < 2; ++j)
                *(uint4*)((char*)lA + (size_t)(j * 256 + t) * 16) = aR[j];
            #pragma unroll
            for (int j = 0; j < 4; ++j) {
                int s = j * 256 + t, r = s >> 4, g = s & 15;
                int gs = g ^ ((r >> 1) & 15);
                *(float4*)((char*)scratch + r * 256 + gs * 16) = bR[j];
            }
            __syncthreads();
            if (it < 7) { LOADA(it * 64 + 64); LOADB(it * 64 + 64); }  // prefetch
            // stage2: transpose-read scratch, cvt, pack into swizzled bf16 lB
            {
                int swz = sp & 15;
                float4 a0 = *(const float4*)((char*)scratch + (2*sp) * 256 + ((2*sj) ^ swz) * 16);
                float4 a1 = *(const float4*)((char*)scratch + (2*sp) * 256 + ((2*sj+1) ^ swz) * 16);
                float4 b0 = *(const float4*)((char*)scratch + (2*sp+1) * 256 + ((2*sj) ^ swz) * 16);
                float4 b1 = *(const float4*)((char*)scratch + (2*sp+1) * 256 + ((2*sj+1) ^ swz) * 16);
                float c0v[8] = {a0.x, a0.y, a0.z, a0.w, a1.x, a1.y, a1.z, a1.w};
                float c1v[8] = {b0.x, b0.y, b0.z, b0.w, b1.x, b1.y, b1.z, b1.w};
                #pragma unroll
                for (int w = 0; w < 8; ++w) {
                    int n = sj * 8 + w;
                    unsigned pk = (unsigned)f2bf(c0v[w]) | ((unsigned)f2bf(c1v[w]) << 16);
                    *(unsigned*)((char*)lB + n * 128 + (((sp >> 2) ^ (n & 7)) * 16) + (sp & 3) * 4) = pk;
                }
            }
            __syncthreads();
            #pragma unroll
            for (int ks = 0; ks < 2; ++ks) {
                bf16x8 av[2], bv[2];
                #pragma unroll
                for (int mi = 0; mi < 2; ++mi) {
                    int ar = wr * 32 + mi * 16 + lr;
                    int q = (ks * 4 + lg) ^ (ar & 7);
                    av[mi] = *(const bf16x8*)((const char*)lA + ar * 128 + q * 16);
                }
                #pragma unroll
                for (int ni = 0; ni < 2; ++ni) {
                    int br = wc * 32 + ni * 16 + lr;
                    int q = (ks * 4 + lg) ^ (br & 7);
                    bv[ni] = *(const bf16x8*)((const char*)lB + br * 128 + q * 16);
                }
                #pragma unroll
                for (int mi = 0; mi < 2; ++mi)
                    #pragma unroll
                    for (int ni = 0; ni < 2; ++ni)
                        acc[mi][ni] = __builtin_amdgcn_mfma_f32_16x16x32_bf16(
                            av[mi], bv[ni], acc[mi][ni], 0, 0, 0);
            }
            __syncthreads();
        }
        int orow = row0 + wr * 32, ocol = col0 + wc * 32 + lr;
        #pragma unroll
        for (int mi = 0; mi < 2; ++mi) {
            int rb = orow + mi * 16 + lg * 4;
            float4 b4 = *(const float4*)&b_kv[rb];
            float bvr[4] = {b4.x, b4.y, b4.z, b4.w};
            #pragma unroll
            for (int ni = 0; ni < 2; ++ni) {
                int cc = ocol + ni * 16;
                #pragma unroll
                for (int r = 0; r < 4; ++r)
                    kv16[((size_t)b * 256 + rb + r) * 1024 + cc] = f2bf(acc[mi][ni][r] + bvr[r]);
            }
        }
    } else {
        int sid = bid - 1024;            // 0..2047
        int bg = sid >> 2, q = sid & 3;  // (b,g), quarter (2 channels)
        const float4* xp = (const float4*)(x + (size_t)bg * 32768 + q * 8192);
        float s = 0.f, ss = 0.f;
        #pragma unroll
        for (int j = 0; j < 8; ++j) {
            float4 v = xp[t + 256 * j];
            s  += v.x + v.y + v.z + v.w;
            ss += v.x*v.x + v.y*v.y + v.z*v.z + v.w*v.w;
        }
        #pragma unroll
        for (int off = 32; off > 0; off >>= 1) {
            s  += __shfl_down(s, off, 64);
            ss += __shfl_down(ss, off, 64);
        }
        int wave = t >> 6;
        if ((t & 63) == 0) { red[wave * 2] = s; red[wave * 2 + 1] = ss; }
        __syncthreads();
        if (t == 0) {
            float S  = red[0] + red[2] + red[4] + red[6];
            float SS = red[1] + red[3] + red[5] + red[7];
            atomicAdd(&statacc[bg * 2],     S);
            atomicAdd(&statacc[bg * 2 + 1], SS);
        }
    }
}

// ---------------------------------------------------------------------------
// L3: partial context, UNNORMALIZED: ctx[d,e] += sum_n exp(k[d,n]) v[e,n],
// rowsum[d] += sum_n exp(k[d,n]).  grid (8 nchunks, 64 bh).
__global__ __launch_bounds__(256) void ctx_partial_kernel(const ushort* __restrict__ kv,
                                                          float* __restrict__ rowsum,
                                                          float* __restrict__ ctx) {
    int bh = blockIdx.y, b = bh >> 2, h = bh & 3;
    int n0 = blockIdx.x * 128;
    __shared__ float pl[32][129], vl[32][129];
    int t = threadIdx.x;
    int r = t >> 3, cs = (t & 7) * 16;
    const ushort* kp = kv + ((size_t)b * 256 + h * 32 + r) * 1024 + n0 + cs;
    const ushort* vp = kv + ((size_t)b * 256 + 128 + h * 32 + r) * 1024 + n0 + cs;
    float kvals[16], vvals[16];
    unpack8(((const uint4*)kp)[0], kvals);
    unpack8(((const uint4*)kp)[1], kvals + 8);
    unpack8(((const uint4*)vp)[0], vvals);
    unpack8(((const uint4*)vp)[1], vvals + 8);
    float psum = 0.f;
    #pragma unroll
    for (int i = 0; i < 16; ++i) {
        float e = __expf(kvals[i]);
        pl[r][cs + i] = e;
        vl[r][cs + i] = vvals[i];
        psum += e;
    }
    psum += __shfl_xor(psum, 1, 64);
    psum += __shfl_xor(psum, 2, 64);
    psum += __shfl_xor(psum, 4, 64);
    if ((t & 7) == 0) atomicAdd(&rowsum[bh * 32 + r], psum);
    __syncthreads();
    int d0 = t >> 5, e0 = t & 31;
    float acc[4] = {0.f, 0.f, 0.f, 0.f};
    #pragma unroll 8
    for (int nn = 0; nn < 128; ++nn) {
        float vv = vl[e0][nn];
        #pragma unroll
        for (int i = 0; i < 4; ++i)
            acc[i] += pl[d0 + 8 * i][nn] * vv;
    }
    #pragma unroll
    for (int i = 0; i < 4; ++i)
        atomicAdd(&ctx[((size_t)bh * 32 + d0 + 8 * i) * 32 + e0], acc[i]);
}

// ---------------------------------------------------------------------------
// L4: A-fold: normalize ctx by rowsum, M = w_out@ctx^T in LDS, then
// A16[b,o,c] = bf16(wt*s), biasb[b,o] = sum_c wt*t + M.b_q + b_out
__global__ __launch_bounds__(256) void a_kernel(const float* __restrict__ ctx,
                                                const float* __restrict__ rowsum,
                                                const float* __restrict__ w_out,
                                                const float* __restrict__ w_q,
                                                const float* __restrict__ b_q,
                                                const float* __restrict__ statacc,
                                                const float* __restrict__ gn_w,
                                                const float* __restrict__ gn_b,
                                                const float* __restrict__ b_out,
                                                ushort* __restrict__ A16,
                                                float* __restrict__ biasb) {
    __shared__ float ctxl[4][32][33];
    __shared__ float wol[16][128];
    __shared__ float ml[16][128];
    __shared__ float cbuf[256][17];
    __shared__ float pbuf[16][17];
    int b = blockIdx.x >> 4, ot = (blockIdx.x & 15) << 4;
    int t = threadIdx.x;
    #pragma unroll
    for (int j = 0; j < 16; ++j) {
        int e = t + 256 * j;            // 0..4095
        float inv = 1.f / rowsum[b * 128 + (e >> 5)];
        ctxl[e >> 10][(e >> 5) & 31][e & 31] = ctx[(size_t)b * 4096 + e] * inv;
    }
    #pragma unroll
    for (int j = 0; j < 8; ++j) {
        int e = t + 256 * j;            // 0..2047
        wol[e >> 7][e & 127] = w_out[(ot + (e >> 7)) * 128 + (e & 127)];
    }
    __syncthreads();
    #pragma unroll
    for (int j = 0; j < 8; ++j) {
        int e = t + 256 * j;
        int o = e >> 7, hd = e & 127, h = hd >> 5, d = hd & 31;
        float acc = 0.f;
        #pragma unroll
        for (int ee = 0; ee < 32; ++ee) acc += wol[o][h * 32 + ee] * ctxl[h][d][ee];
        ml[o][hd] = acc;
    }
    __syncthreads();
    int c = t, g = c >> 3;
    float a0 = statacc[(b * 32 + g) * 2], a1 = statacc[(b * 32 + g) * 2 + 1];
    float mu  = a0 * (1.f / 32768.f);
    float var = a1 * (1.f / 32768.f) - mu * mu;
    float sc = rsqrtf(var + 1e-5f) * gn_w[c];
    float tc = gn_b[c] - mu * sc;
    float wt[16];
    #pragma unroll
    for (int o = 0; o < 16; ++o) wt[o] = 0.f;
    for (int hd = 0; hd < 128; ++hd) {
        float wq = w_q[hd * 256 + c];
        #pragma unroll
        for (int o = 0; o < 16; ++o) wt[o] += ml[o][hd] * wq;
    }
    ushort* Abp = A16 + ((size_t)b * 256 + ot) * 256 + c;
    #pragma unroll
    for (int o = 0; o < 16; ++o) {
        Abp[(size_t)o * 256] = f2bf(wt[o] * sc);
        cbuf[c][o] = wt[o] * tc;
    }
    __syncthreads();
    {
        int o = t >> 4, seg = t & 15;
        float p = 0.f;
        #pragma unroll
        for (int i = 0; i < 16; ++i) p += cbuf[seg * 16 + i][o];
        pbuf[o][seg] = p;
    }
    __syncthreads();
    if (t < 16) {
        int o = t;
        float sum = 0.f;
        #pragma unroll
        for (int s2 = 0; s2 < 16; ++s2) sum += pbuf[o][s2];
        float md = 0.f;
        #pragma unroll 8
        for (int hd = 0; hd < 128; ++hd) md += ml[o][hd] * b_q[hd];
        biasb[(size_t)b * 256 + ot + o] = sum + md + b_out[ot + o];
    }
}

// ---------------------------------------------------------------------------
// L5: out = A16 @ x^T + bias.  BM=256, BN=128, BK=64; 8 waves (4x2), 512 thr.
// A and B reg-staged with next-tile prefetch; B transposed via swizzled scratch.
__global__ __launch_bounds__(512) void out_gemm_fused(const ushort* __restrict__ A16,
                                                      const float* __restrict__ x,
                                                      const float* __restrict__ biasb,
                                                      float* __restrict__ out) {
    __shared__ ushort lA[256 * 64];     // 32 KB
    __shared__ ushort lB[128 * 64];     // 16 KB
    __shared__ float scratch[64 * 128]; // 32 KB, granule-swizzled
    int b = blockIdx.y;
    int n0 = blockIdx.x * 128;
    int t = threadIdx.x;
    int l = t & 63, wid = t >> 6;
    int wr = wid >> 1, wc = wid & 1;          // 4 x 2 wave grid
    int lr = l & 15, lg = l >> 4;
    const ushort* Ab = A16 + (size_t)b * 65536;
    const float* xb = x + (size_t)b * 256 * 4096 + n0;
    int sp = t & 31, sj = t >> 5;             // c-pair (2sp,2sp+1), n-octet (16)
    uint4 aR[4]; float4 bR[4];
    auto LOADA = [&](int k0) {
        #pragma unroll
        for (int j = 0; j < 4; ++j) {
            int gi = j * 512 + t, r = gi >> 3, g = (gi & 7) ^ (r & 7);
            aR[j] = *(const uint4*)(Ab + (size_t)r * 256 + k0 + g * 8);
        }
    };
    auto LOADB = [&](int k0) {
        #pragma unroll
        for (int j = 0; j < 4; ++j) {
            int s = j * 512 + t, r = s >> 5, g = s & 31;
            bR[j] = *(const float4*)&xb[(size_t)(k0 + r) * 4096 + g * 4];
        }
    };
    LOADA(0); LOADB(0);
    f32x4 acc[4][4] = {};
    for (int it = 0; it < 4; ++it) {
        #pragma unroll
        for (int j = 0; j < 4; ++j)
            *(uint4*)((char*)lA + (size_t)(j * 512 + t) * 16) = aR[j];
        #pragma unroll
        for (int j = 0; j < 4; ++j) {
            int s = j * 512 + t, r = s >> 5, g = s & 31;
            int gs = g ^ ((r >> 1) & 31);
            *(float4*)((char*)scratch + r * 512 + gs * 16) = bR[j];
        }
        __syncthreads();
        if (it < 3) { LOADA(it * 64 + 64); LOADB(it * 64 + 64); }   // prefetch
        // stage2: transpose-read, cvt, pack into swizzled bf16 lB
        {
            int swz = sp & 31;
            float4 a0 = *(const float4*)((char*)scratch + (2*sp) * 512 + ((2*sj) ^ swz) * 16);
            float4 a1 = *(const float4*)((char*)scratch + (2*sp) * 512 + ((2*sj+1) ^ swz) * 16);
            float4 b0 = *(const float4*)((char*)scratch + (2*sp+1) * 512 + ((2*sj) ^ swz) * 16);
            float4 b1 = *(const float4*)((char*)scratch + (2*sp+1) * 512 + ((2*sj+1) ^ swz) * 16);
            float c0v[8] = {a0.x, a0.y, a0.z, a0.w, a1.x, a1.y, a1.z, a1.w};
            float c1v[8] = {b0.x, b0.y, b0.z, b0.w, b1.x, b1.y, b1.z, b1.w};
            #pragma unroll
            for (int w = 0; w < 8; ++w) {
                int n = sj * 8 + w;
                unsigned pk = (unsigned)f2bf(c0v[w]) | ((unsigned)f2bf(c1v[w]) << 16);
                *(unsigned*)((char*)lB + n * 128 + (((sp >> 2) ^ (n & 7)) * 16) + (sp & 3) * 4) = pk;
            }
        }
        __syncthreads();
        #pragma unroll
        for (int ks = 0; ks < 2; ++ks) {
            bf16x8 av[4], bv[4];
            #pragma unroll
            for (int mi = 0; mi < 4; ++mi) {
                int ar = wr * 64 + mi * 16 + lr;
                int q = (ks * 4 + lg) ^ (ar & 7);
                av[mi] = *(const bf16x8*)((const char*)lA + ar * 128 + q * 16);
            }
            #pragma unroll
            for (int ni = 0; ni < 4; ++ni) {
                int br = wc * 64 + ni * 16 + lr;
                int q = (ks * 4 + lg) ^ (br & 7);
                bv[ni] = *(const bf16x8*)((const char*)lB + br * 128 + q * 16);
            }
            #pragma unroll
            for (int mi = 0; mi < 4; ++mi)
                #pragma unroll
                for (int ni = 0; ni < 4; ++ni)
                    acc[mi][ni] = __builtin_amdgcn_mfma_f32_16x16x32_bf16(
                        av[mi], bv[ni], acc[mi][ni], 0, 0, 0);
        }
        __syncthreads();
    }
    const float* bp = biasb + (size_t)b * 256;
    int orow = wr * 64, ocol = n0 + wc * 64 + lr;
    #pragma unroll
    for (int mi = 0; mi < 4; ++mi) {
        int rb = orow + mi * 16 + lg * 4;
        float4 b4 = *(const float4*)&bp[rb];
        float bvr[4] = {b4.x, b4.y, b4.z, b4.w};
        #pragma unroll
        for (int ni = 0; ni < 4; ++ni) {
            int cc = ocol + ni * 16;
            #pragma unroll
            for (int r = 0; r < 4; ++r)
                out[((size_t)b * 256 + rb + r) * 4096 + cc] = acc[mi][ni][r] + bvr[r];
        }
    }
}

extern "C" void kernel_launch(void* const* d_in, const int* in_sizes, int n_in,
                              void* d_out, int out_size, void* d_ws, size_t ws_size,
                              hipStream_t stream) {
    const float* x     = (const float*)d_in[0];
    const float* cond  = (const float*)d_in[1];
    const float* gn_w  = (const float*)d_in[2];
    const float* gn_b  = (const float*)d_in[3];
    const float* w_q   = (const float*)d_in[4];
    const float* b_q   = (const float*)d_in[5];
    const float* w_kv  = (const float*)d_in[6];
    const float* b_kv  = (const float*)d_in[7];
    const float* w_out = (const float*)d_in[8];
    const float* b_out = (const float*)d_in[9];
    float* out = (float*)d_out;

    float* f       = (float*)d_ws;
    float* statacc = f;                     // 1024 floats
    float* rowsum  = f + 1024;              // 2048 floats
    float* ctx     = f + 3072;              // 65536 floats
    float* biasb   = f + 68608;             // 4096 floats
    ushort* u      = (ushort*)(f + 72704);
    ushort* wkv16  = u;                     // 131072
    ushort* kv16   = u + 131072;            // 4194304
    ushort* A16    = u + 4325376;           // 1048576

    // L1: zero accumulators + convert w_kv
    cvtw_kernel<<<512, 256, 0, stream>>>(w_kv, wkv16, statacc);
    // L2: kv GEMM (reg-staged, prefetch-pipelined) + GN stats, one dispatch
    kvstats_kernel<<<3072, 256, 0, stream>>>(wkv16, cond, b_kv, kv16, x, statacc);
    // L3: unnormalized context + row sums
    ctx_partial_kernel<<<dim3(8, 64), 256, 0, stream>>>(kv16, rowsum, ctx);
    // L4: fold everything into per-batch A (bf16) + bias
    a_kernel<<<256, 256, 0, stream>>>(ctx, rowsum, w_out, w_q, b_q, statacc,
                                      gn_w, gn_b, b_out, A16, biasb);
    // L5: out = A @ x^T + bias (reg-staged, prefetch-pipelined)
    out_gemm_fused<<<dim3(32, 16), 512, 0, stream>>>(A16, x, biasb, out);
}

// Round 11
// 85.922 us; speedup vs baseline: 1.7664x; 1.7664x over previous
//
#include <hip/hip_runtime.h>
#include <hip/hip_bf16.h>

typedef __attribute__((ext_vector_type(8))) short bf16x8;
typedef __attribute__((ext_vector_type(4))) float f32x4;

__device__ __forceinline__ ushort f2bf(float f) {
    __hip_bfloat16 h = __float2bfloat16(f);
    return __builtin_bit_cast(ushort, h);
}
__device__ __forceinline__ float bflo(unsigned u) { return __uint_as_float(u << 16); }
__device__ __forceinline__ float bfhi(unsigned u) { return __uint_as_float(u & 0xffff0000u); }

__device__ __forceinline__ void unpack8(uint4 r, float* o) {
    o[0] = bflo(r.x); o[1] = bfhi(r.x); o[2] = bflo(r.y); o[3] = bfhi(r.y);
    o[4] = bflo(r.z); o[5] = bfhi(r.z); o[6] = bflo(r.w); o[7] = bfhi(r.w);
}

// ---------------------------------------------------------------------------
// L1: convert w_kv to bf16 AND zero atomic accumulators
__global__ void cvtw_kernel(const float* __restrict__ w, ushort* __restrict__ o,
                            float* __restrict__ zbase) {
    int i = blockIdx.x * 256 + threadIdx.x;      // 0..131071
    if (i < 68608) zbase[i] = 0.f;
    o[i] = f2bf(w[i]);
}

// ---------------------------------------------------------------------------
// L2 merged: blocks [0,1024): kv = w_kv @ cond (64x64 MFMA tiles); A and B
//   reg-staged (NAMED regs, no arrays/lambdas) with next-tile prefetch.
//   blocks [1024,3072): GroupNorm sums for x, one block per (b,g)-quarter.
__global__ __launch_bounds__(256) void kvstats_kernel(const ushort* __restrict__ wkv16,
                                                      const float* __restrict__ cond,
                                                      const float* __restrict__ b_kv,
                                                      ushort* __restrict__ kv16,
                                                      const float* __restrict__ x,
                                                      float* __restrict__ statacc) {
    __shared__ ushort lA[64 * 64];      // 8 KB
    __shared__ ushort lB[64 * 64];      // 8 KB
    __shared__ float scratch[64 * 64];  // 16 KB, granule-swizzled
    __shared__ float red[8];
    int bid = blockIdx.x;
    int t = threadIdx.x;
    if (bid < 1024) {
        int nb = bid & 15, ob = (bid >> 4) & 3, b = bid >> 6;
        int col0 = nb * 64, row0 = ob * 64;
        int l = t & 63, wid = t >> 6;
        int wr = wid >> 1, wc = wid & 1;
        int lr = l & 15, lg = l >> 4;
        const ushort* Ab = wkv16 + (size_t)row0 * 512;
        const float* Bb = cond + (size_t)b * 512 * 1024 + col0;
        int sp = t & 31, sj = t >> 5;   // c-pair (2sp,2sp+1), n-octet sj*8
        // named staging registers (rule #20: no arrays)
        uint4 a0_, a1_;
        float4 b0_, b1_, b2_, b3_;
        int rA0 = t >> 3,        gA0 = (t & 7) ^ (rA0 & 7);
        int rA1 = 32 + (t >> 3), gA1 = (t & 7) ^ (rA1 & 7);
        int rB = t >> 4, gB = t & 15;
#define KV_LOADA(k0) { \
        a0_ = *(const uint4*)(Ab + (size_t)rA0 * 512 + (k0) + gA0 * 8); \
        a1_ = *(const uint4*)(Ab + (size_t)rA1 * 512 + (k0) + gA1 * 8); }
#define KV_LOADB(k0) { \
        b0_ = *(const float4*)&Bb[(size_t)((k0) + rB)      * 1024 + gB * 4]; \
        b1_ = *(const float4*)&Bb[(size_t)((k0) + 16 + rB) * 1024 + gB * 4]; \
        b2_ = *(const float4*)&Bb[(size_t)((k0) + 32 + rB) * 1024 + gB * 4]; \
        b3_ = *(const float4*)&Bb[(size_t)((k0) + 48 + rB) * 1024 + gB * 4]; }
        KV_LOADA(0); KV_LOADB(0);
        f32x4 acc00 = {}, acc01 = {}, acc10 = {}, acc11 = {};
        for (int it = 0; it < 8; ++it) {
            *(uint4*)((char*)lA + (size_t)t * 16) = a0_;
            *(uint4*)((char*)lA + (size_t)(256 + t) * 16) = a1_;
            *(float4*)((char*)scratch + (rB)      * 256 + (gB ^ (((rB)      >> 1) & 15)) * 16) = b0_;
            *(float4*)((char*)scratch + (16 + rB) * 256 + (gB ^ (((16 + rB) >> 1) & 15)) * 16) = b1_;
            *(float4*)((char*)scratch + (32 + rB) * 256 + (gB ^ (((32 + rB) >> 1) & 15)) * 16) = b2_;
            *(float4*)((char*)scratch + (48 + rB) * 256 + (gB ^ (((48 + rB) >> 1) & 15)) * 16) = b3_;
            __syncthreads();
            if (it < 7) { KV_LOADA(it * 64 + 64); KV_LOADB(it * 64 + 64); }  // prefetch
            {
                int swz = sp & 15;
                float4 s0 = *(const float4*)((char*)scratch + (2*sp)   * 256 + ((2*sj)   ^ swz) * 16);
                float4 s1 = *(const float4*)((char*)scratch + (2*sp)   * 256 + ((2*sj+1) ^ swz) * 16);
                float4 s2 = *(const float4*)((char*)scratch + (2*sp+1) * 256 + ((2*sj)   ^ swz) * 16);
                float4 s3 = *(const float4*)((char*)scratch + (2*sp+1) * 256 + ((2*sj+1) ^ swz) * 16);
                float c0v[8] = {s0.x, s0.y, s0.z, s0.w, s1.x, s1.y, s1.z, s1.w};
                float c1v[8] = {s2.x, s2.y, s2.z, s2.w, s3.x, s3.y, s3.z, s3.w};
                #pragma unroll
                for (int w = 0; w < 8; ++w) {
                    int n = sj * 8 + w;
                    unsigned pk = (unsigned)f2bf(c0v[w]) | ((unsigned)f2bf(c1v[w]) << 16);
                    *(unsigned*)((char*)lB + n * 128 + (((sp >> 2) ^ (n & 7)) * 16) + (sp & 3) * 4) = pk;
                }
            }
            __syncthreads();
            #pragma unroll
            for (int ks = 0; ks < 2; ++ks) {
                bf16x8 av0, av1, bv0, bv1;
                {
                    int ar = wr * 32 + lr, q = (ks * 4 + lg) ^ (ar & 7);
                    av0 = *(const bf16x8*)((const char*)lA + ar * 128 + q * 16);
                }
                {
                    int ar = wr * 32 + 16 + lr, q = (ks * 4 + lg) ^ (ar & 7);
                    av1 = *(const bf16x8*)((const char*)lA + ar * 128 + q * 16);
                }
                {
                    int br = wc * 32 + lr, q = (ks * 4 + lg) ^ (br & 7);
                    bv0 = *(const bf16x8*)((const char*)lB + br * 128 + q * 16);
                }
                {
                    int br = wc * 32 + 16 + lr, q = (ks * 4 + lg) ^ (br & 7);
                    bv1 = *(const bf16x8*)((const char*)lB + br * 128 + q * 16);
                }
                acc00 = __builtin_amdgcn_mfma_f32_16x16x32_bf16(av0, bv0, acc00, 0, 0, 0);
                acc01 = __builtin_amdgcn_mfma_f32_16x16x32_bf16(av0, bv1, acc01, 0, 0, 0);
                acc10 = __builtin_amdgcn_mfma_f32_16x16x32_bf16(av1, bv0, acc10, 0, 0, 0);
                acc11 = __builtin_amdgcn_mfma_f32_16x16x32_bf16(av1, bv1, acc11, 0, 0, 0);
            }
            __syncthreads();
        }
#undef KV_LOADA
#undef KV_LOADB
        int orow = row0 + wr * 32, ocol = col0 + wc * 32 + lr;
        #pragma unroll
        for (int mi = 0; mi < 2; ++mi) {
            int rb = orow + mi * 16 + lg * 4;
            float4 b4 = *(const float4*)&b_kv[rb];
            float bvr[4] = {b4.x, b4.y, b4.z, b4.w};
            f32x4 aacc0 = mi == 0 ? acc00 : acc10;
            f32x4 aacc1 = mi == 0 ? acc01 : acc11;
            #pragma unroll
            for (int r = 0; r < 4; ++r) {
                kv16[((size_t)b * 256 + rb + r) * 1024 + ocol]      = f2bf(aacc0[r] + bvr[r]);
                kv16[((size_t)b * 256 + rb + r) * 1024 + ocol + 16] = f2bf(aacc1[r] + bvr[r]);
            }
        }
    } else {
        int sid = bid - 1024;            // 0..2047
        int bg = sid >> 2, q = sid & 3;  // (b,g), quarter (2 channels)
        const float4* xp = (const float4*)(x + (size_t)bg * 32768 + q * 8192);
        float s = 0.f, ss = 0.f;
        #pragma unroll
        for (int j = 0; j < 8; ++j) {
            float4 v = xp[t + 256 * j];
            s  += v.x + v.y + v.z + v.w;
            ss += v.x*v.x + v.y*v.y + v.z*v.z + v.w*v.w;
        }
        #pragma unroll
        for (int off = 32; off > 0; off >>= 1) {
            s  += __shfl_down(s, off, 64);
            ss += __shfl_down(ss, off, 64);
        }
        int wave = t >> 6;
        if ((t & 63) == 0) { red[wave * 2] = s; red[wave * 2 + 1] = ss; }
        __syncthreads();
        if (t == 0) {
            float S  = red[0] + red[2] + red[4] + red[6];
            float SS = red[1] + red[3] + red[5] + red[7];
            atomicAdd(&statacc[bg * 2],     S);
            atomicAdd(&statacc[bg * 2 + 1], SS);
        }
    }
}

// ---------------------------------------------------------------------------
// L3: partial context, UNNORMALIZED: ctx[d,e] += sum_n exp(k[d,n]) v[e,n],
// rowsum[d] += sum_n exp(k[d,n]).  grid (8 nchunks, 64 bh).
__global__ __launch_bounds__(256) void ctx_partial_kernel(const ushort* __restrict__ kv,
                                                          float* __restrict__ rowsum,
                                                          float* __restrict__ ctx) {
    int bh = blockIdx.y, b = bh >> 2, h = bh & 3;
    int n0 = blockIdx.x * 128;
    __shared__ float pl[32][129], vl[32][129];
    int t = threadIdx.x;
    int r = t >> 3, cs = (t & 7) * 16;
    const ushort* kp = kv + ((size_t)b * 256 + h * 32 + r) * 1024 + n0 + cs;
    const ushort* vp = kv + ((size_t)b * 256 + 128 + h * 32 + r) * 1024 + n0 + cs;
    float kvals[16], vvals[16];
    unpack8(((const uint4*)kp)[0], kvals);
    unpack8(((const uint4*)kp)[1], kvals + 8);
    unpack8(((const uint4*)vp)[0], vvals);
    unpack8(((const uint4*)vp)[1], vvals + 8);
    float psum = 0.f;
    #pragma unroll
    for (int i = 0; i < 16; ++i) {
        float e = __expf(kvals[i]);
        pl[r][cs + i] = e;
        vl[r][cs + i] = vvals[i];
        psum += e;
    }
    psum += __shfl_xor(psum, 1, 64);
    psum += __shfl_xor(psum, 2, 64);
    psum += __shfl_xor(psum, 4, 64);
    if ((t & 7) == 0) atomicAdd(&rowsum[bh * 32 + r], psum);
    __syncthreads();
    int d0 = t >> 5, e0 = t & 31;
    float acc[4] = {0.f, 0.f, 0.f, 0.f};
    #pragma unroll 8
    for (int nn = 0; nn < 128; ++nn) {
        float vv = vl[e0][nn];
        #pragma unroll
        for (int i = 0; i < 4; ++i)
            acc[i] += pl[d0 + 8 * i][nn] * vv;
    }
    #pragma unroll
    for (int i = 0; i < 4; ++i)
        atomicAdd(&ctx[((size_t)bh * 32 + d0 + 8 * i) * 32 + e0], acc[i]);
}

// ---------------------------------------------------------------------------
// L4: A-fold: normalize ctx by rowsum, M = w_out@ctx^T in LDS, then
// A16[b,o,c] = bf16(wt*s), biasb[b,o] = sum_c wt*t + M.b_q + b_out
__global__ __launch_bounds__(256) void a_kernel(const float* __restrict__ ctx,
                                                const float* __restrict__ rowsum,
                                                const float* __restrict__ w_out,
                                                const float* __restrict__ w_q,
                                                const float* __restrict__ b_q,
                                                const float* __restrict__ statacc,
                                                const float* __restrict__ gn_w,
                                                const float* __restrict__ gn_b,
                                                const float* __restrict__ b_out,
                                                ushort* __restrict__ A16,
                                                float* __restrict__ biasb) {
    __shared__ float ctxl[4][32][33];
    __shared__ float wol[16][128];
    __shared__ float ml[16][128];
    __shared__ float cbuf[256][17];
    __shared__ float pbuf[16][17];
    int b = blockIdx.x >> 4, ot = (blockIdx.x & 15) << 4;
    int t = threadIdx.x;
    #pragma unroll
    for (int j = 0; j < 16; ++j) {
        int e = t + 256 * j;            // 0..4095
        float inv = 1.f / rowsum[b * 128 + (e >> 5)];
        ctxl[e >> 10][(e >> 5) & 31][e & 31] = ctx[(size_t)b * 4096 + e] * inv;
    }
    #pragma unroll
    for (int j = 0; j < 8; ++j) {
        int e = t + 256 * j;            // 0..2047
        wol[e >> 7][e & 127] = w_out[(ot + (e >> 7)) * 128 + (e & 127)];
    }
    __syncthreads();
    #pragma unroll
    for (int j = 0; j < 8; ++j) {
        int e = t + 256 * j;
        int o = e >> 7, hd = e & 127, h = hd >> 5, d = hd & 31;
        float acc = 0.f;
        #pragma unroll
        for (int ee = 0; ee < 32; ++ee) acc += wol[o][h * 32 + ee] * ctxl[h][d][ee];
        ml[o][hd] = acc;
    }
    __syncthreads();
    int c = t, g = c >> 3;
    float a0 = statacc[(b * 32 + g) * 2], a1 = statacc[(b * 32 + g) * 2 + 1];
    float mu  = a0 * (1.f / 32768.f);
    float var = a1 * (1.f / 32768.f) - mu * mu;
    float sc = rsqrtf(var + 1e-5f) * gn_w[c];
    float tc = gn_b[c] - mu * sc;
    float wt[16];
    #pragma unroll
    for (int o = 0; o < 16; ++o) wt[o] = 0.f;
    for (int hd = 0; hd < 128; ++hd) {
        float wq = w_q[hd * 256 + c];
        #pragma unroll
        for (int o = 0; o < 16; ++o) wt[o] += ml[o][hd] * wq;
    }
    ushort* Abp = A16 + ((size_t)b * 256 + ot) * 256 + c;
    #pragma unroll
    for (int o = 0; o < 16; ++o) {
        Abp[(size_t)o * 256] = f2bf(wt[o] * sc);
        cbuf[c][o] = wt[o] * tc;
    }
    __syncthreads();
    {
        int o = t >> 4, seg = t & 15;
        float p = 0.f;
        #pragma unroll
        for (int i = 0; i < 16; ++i) p += cbuf[seg * 16 + i][o];
        pbuf[o][seg] = p;
    }
    __syncthreads();
    if (t < 16) {
        int o = t;
        float sum = 0.f;
        #pragma unroll
        for (int s2 = 0; s2 < 16; ++s2) sum += pbuf[o][s2];
        float md = 0.f;
        #pragma unroll 8
        for (int hd = 0; hd < 128; ++hd) md += ml[o][hd] * b_q[hd];
        biasb[(size_t)b * 256 + ot + o] = sum + md + b_out[ot + o];
    }
}

// ---------------------------------------------------------------------------
// L5: out = A16 @ x^T + bias.  BM=256, BN=128, BK=64; 8 waves (4x2), 512 thr.
// A and B reg-staged via NAMED regs with next-tile prefetch.
__global__ __launch_bounds__(512) void out_gemm_fused(const ushort* __restrict__ A16,
                                                      const float* __restrict__ x,
                                                      const float* __restrict__ biasb,
                                                      float* __restrict__ out) {
    __shared__ ushort lA[256 * 64];     // 32 KB
    __shared__ ushort lB[128 * 64];     // 16 KB
    __shared__ float scratch[64 * 128]; // 32 KB, granule-swizzled
    int b = blockIdx.y;
    int n0 = blockIdx.x * 128;
    int t = threadIdx.x;
    int l = t & 63, wid = t >> 6;
    int wr = wid >> 1, wc = wid & 1;          // 4 x 2 wave grid
    int lr = l & 15, lg = l >> 4;
    const ushort* Ab = A16 + (size_t)b * 65536;
    const float* xb = x + (size_t)b * 256 * 4096 + n0;
    int sp = t & 31, sj = t >> 5;             // c-pair (2sp,2sp+1), n-octet (16)
    uint4 a0_, a1_, a2_, a3_;
    float4 b0_, b1_, b2_, b3_;
    int rA = t >> 3, gA = (t & 7) ^ (rA & 7); // (64k+rA)&7 == rA&7
    int rB = t >> 5, gB = t & 31;
#define OG_LOADA(k0) { \
    a0_ = *(const uint4*)(Ab + (size_t)(rA)       * 256 + (k0) + gA * 8); \
    a1_ = *(const uint4*)(Ab + (size_t)(64 + rA)  * 256 + (k0) + gA * 8); \
    a2_ = *(const uint4*)(Ab + (size_t)(128 + rA) * 256 + (k0) + gA * 8); \
    a3_ = *(const uint4*)(Ab + (size_t)(192 + rA) * 256 + (k0) + gA * 8); }
#define OG_LOADB(k0) { \
    b0_ = *(const float4*)&xb[(size_t)((k0) + rB)      * 4096 + gB * 4]; \
    b1_ = *(const float4*)&xb[(size_t)((k0) + 16 + rB) * 4096 + gB * 4]; \
    b2_ = *(const float4*)&xb[(size_t)((k0) + 32 + rB) * 4096 + gB * 4]; \
    b3_ = *(const float4*)&xb[(size_t)((k0) + 48 + rB) * 4096 + gB * 4]; }
    OG_LOADA(0); OG_LOADB(0);
    f32x4 acc[4][4] = {};
    for (int it = 0; it < 4; ++it) {
        *(uint4*)((char*)lA + (size_t)t * 16)          = a0_;
        *(uint4*)((char*)lA + (size_t)(512 + t) * 16)  = a1_;
        *(uint4*)((char*)lA + (size_t)(1024 + t) * 16) = a2_;
        *(uint4*)((char*)lA + (size_t)(1536 + t) * 16) = a3_;
        *(float4*)((char*)scratch + (rB)      * 512 + (gB ^ (((rB)      >> 1) & 31)) * 16) = b0_;
        *(float4*)((char*)scratch + (16 + rB) * 512 + (gB ^ (((16 + rB) >> 1) & 31)) * 16) = b1_;
        *(float4*)((char*)scratch + (32 + rB) * 512 + (gB ^ (((32 + rB) >> 1) & 31)) * 16) = b2_;
        *(float4*)((char*)scratch + (48 + rB) * 512 + (gB ^ (((48 + rB) >> 1) & 31)) * 16) = b3_;
        __syncthreads();
        if (it < 3) { OG_LOADA(it * 64 + 64); OG_LOADB(it * 64 + 64); }   // prefetch
        {
            int swz = sp & 31;
            float4 s0 = *(const float4*)((char*)scratch + (2*sp)   * 512 + ((2*sj)   ^ swz) * 16);
            float4 s1 = *(const float4*)((char*)scratch + (2*sp)   * 512 + ((2*sj+1) ^ swz) * 16);
            float4 s2 = *(const float4*)((char*)scratch + (2*sp+1) * 512 + ((2*sj)   ^ swz) * 16);
            float4 s3 = *(const float4*)((char*)scratch + (2*sp+1) * 512 + ((2*sj+1) ^ swz) * 16);
            float c0v[8] = {s0.x, s0.y, s0.z, s0.w, s1.x, s1.y, s1.z, s1.w};
            float c1v[8] = {s2.x, s2.y, s2.z, s2.w, s3.x, s3.y, s3.z, s3.w};
            #pragma unroll
            for (int w = 0; w < 8; ++w) {
                int n = sj * 8 + w;
                unsigned pk = (unsigned)f2bf(c0v[w]) | ((unsigned)f2bf(c1v[w]) << 16);
                *(unsigned*)((char*)lB + n * 128 + (((sp >> 2) ^ (n & 7)) * 16) + (sp & 3) * 4) = pk;
            }
        }
        __syncthreads();
        #pragma unroll
        for (int ks = 0; ks < 2; ++ks) {
            bf16x8 av[4], bv[4];
            #pragma unroll
            for (int mi = 0; mi < 4; ++mi) {
                int ar = wr * 64 + mi * 16 + lr;
                int q = (ks * 4 + lg) ^ (ar & 7);
                av[mi] = *(const bf16x8*)((const char*)lA + ar * 128 + q * 16);
            }
            #pragma unroll
            for (int ni = 0; ni < 4; ++ni) {
                int br = wc * 64 + ni * 16 + lr;
                int q = (ks * 4 + lg) ^ (br & 7);
                bv[ni] = *(const bf16x8*)((const char*)lB + br * 128 + q * 16);
            }
            #pragma unroll
            for (int mi = 0; mi < 4; ++mi)
                #pragma unroll
                for (int ni = 0; ni < 4; ++ni)
                    acc[mi][ni] = __builtin_amdgcn_mfma_f32_16x16x32_bf16(
                        av[mi], bv[ni], acc[mi][ni], 0, 0, 0);
        }
        __syncthreads();
    }
#undef OG_LOADA
#undef OG_LOADB
    const float* bp = biasb + (size_t)b * 256;
    int orow = wr * 64, ocol = n0 + wc * 64 + lr;
    #pragma unroll
    for (int mi = 0; mi < 4; ++mi) {
        int rb = orow + mi * 16 + lg * 4;
        float4 b4 = *(const float4*)&bp[rb];
        float bvr[4] = {b4.x, b4.y, b4.z, b4.w};
        #pragma unroll
        for (int ni = 0; ni < 4; ++ni) {
            int cc = ocol + ni * 16;
            #pragma unroll
            for (int r = 0; r < 4; ++r)
                out[((size_t)b * 256 + rb + r) * 4096 + cc] = acc[mi][ni][r] + bvr[r];
        }
    }
}

extern "C" void kernel_launch(void* const* d_in, const int* in_sizes, int n_in,
                              void* d_out, int out_size, void* d_ws, size_t ws_size,
                              hipStream_t stream) {
    const float* x     = (const float*)d_in[0];
    const float* cond  = (const float*)d_in[1];
    const float* gn_w  = (const float*)d_in[2];
    const float* gn_b  = (const float*)d_in[3];
    const float* w_q   = (const float*)d_in[4];
    const float* b_q   = (const float*)d_in[5];
    const float* w_kv  = (const float*)d_in[6];
    const float* b_kv  = (const float*)d_in[7];
    const float* w_out = (const float*)d_in[8];
    const float* b_out = (const float*)d_in[9];
    float* out = (float*)d_out;

    float* f       = (float*)d_ws;
    float* statacc = f;                     // 1024 floats
    float* rowsum  = f + 1024;              // 2048 floats
    float* ctx     = f + 3072;              // 65536 floats
    float* biasb   = f + 68608;             // 4096 floats
    ushort* u      = (ushort*)(f + 72704);
    ushort* wkv16  = u;                     // 131072
    ushort* kv16   = u + 131072;            // 4194304
    ushort* A16    = u + 4325376;           // 1048576

    // L1: zero accumulators + convert w_kv
    cvtw_kernel<<<512, 256, 0, stream>>>(w_kv, wkv16, statacc);
    // L2: kv GEMM (named-reg staged, prefetch-pipelined) + GN stats
    kvstats_kernel<<<3072, 256, 0, stream>>>(wkv16, cond, b_kv, kv16, x, statacc);
    // L3: unnormalized context + row sums
    ctx_partial_kernel<<<dim3(8, 64), 256, 0, stream>>>(kv16, rowsum, ctx);
    // L4: fold everything into per-batch A (bf16) + bias
    a_kernel<<<256, 256, 0, stream>>>(ctx, rowsum, w_out, w_q, b_q, statacc,
                                      gn_w, gn_b, b_out, A16, biasb);
    // L5: out = A @ x^T + bias (named-reg staged, prefetch-pipelined)
    out_gemm_fused<<<dim3(32, 16), 512, 0, stream>>>(A16, x, biasb, out);
}

// Round 12
// 84.102 us; speedup vs baseline: 1.8046x; 1.0216x over previous
//
#include <hip/hip_runtime.h>
#include <hip/hip_bf16.h>

typedef __attribute__((ext_vector_type(8))) short bf16x8;
typedef __attribute__((ext_vector_type(4))) float f32x4;

__device__ __forceinline__ ushort f2bf(float f) {
    __hip_bfloat16 h = __float2bfloat16(f);
    return __builtin_bit_cast(ushort, h);
}
__device__ __forceinline__ float bflo(unsigned u) { return __uint_as_float(u << 16); }
__device__ __forceinline__ float bfhi(unsigned u) { return __uint_as_float(u & 0xffff0000u); }

__device__ __forceinline__ void unpack8(uint4 r, float* o) {
    o[0] = bflo(r.x); o[1] = bfhi(r.x); o[2] = bflo(r.y); o[3] = bfhi(r.y);
    o[4] = bflo(r.z); o[5] = bfhi(r.z); o[6] = bflo(r.w); o[7] = bfhi(r.w);
}

// ---------------------------------------------------------------------------
// L1 prep: blocks [0,512): convert w_kv to bf16 + zero rowsum/ctx;
//          blocks [512,1024): GroupNorm sums, ONE block per (b,g), plain store.
__global__ __launch_bounds__(256) void prep_kernel(const float* __restrict__ w,
                                                   ushort* __restrict__ o,
                                                   float* __restrict__ zbase,
                                                   const float* __restrict__ x,
                                                   float* __restrict__ statacc) {
    __shared__ float red[8];
    int bid = blockIdx.x, t = threadIdx.x;
    if (bid < 512) {
        int i = bid * 256 + t;           // 0..131071
        if (i < 67584) zbase[i] = 0.f;   // rowsum (2048) + ctx (65536)
        o[i] = f2bf(w[i]);
    } else {
        int bg = bid - 512;              // 0..511 = (b,g)
        const float4* xp = (const float4*)(x + (size_t)bg * 32768);
        float s = 0.f, ss = 0.f;
        #pragma unroll
        for (int j = 0; j < 32; ++j) {
            float4 v = xp[t + 256 * j];
            s  += v.x + v.y + v.z + v.w;
            ss += v.x*v.x + v.y*v.y + v.z*v.z + v.w*v.w;
        }
        #pragma unroll
        for (int off = 32; off > 0; off >>= 1) {
            s  += __shfl_down(s, off, 64);
            ss += __shfl_down(ss, off, 64);
        }
        int wave = t >> 6;
        if ((t & 63) == 0) { red[wave * 2] = s; red[wave * 2 + 1] = ss; }
        __syncthreads();
        if (t == 0) {
            statacc[bg * 2]     = red[0] + red[2] + red[4] + red[6];
            statacc[bg * 2 + 1] = red[1] + red[3] + red[5] + red[7];
        }
    }
}

// ---------------------------------------------------------------------------
// L2: kv = w_kv @ cond. BM=128, BN=64, BK=64, K=512. 512 blocks, 4 waves.
// B (cond) staged via named regs, 2-deep prefetch; transposed via fp32 scratch.
__global__ __launch_bounds__(256) void kv_gemm(const ushort* __restrict__ wkv16,
                                               const float* __restrict__ cond,
                                               const float* __restrict__ b_kv,
                                               ushort* __restrict__ kv16) {
    __shared__ ushort lA[128 * 64];     // 16 KB
    __shared__ ushort lB[64 * 64];      // 8 KB
    __shared__ float scratch[64 * 64];  // 16 KB, granule-swizzled
    int nb = blockIdx.x, ob = blockIdx.y, b = blockIdx.z;
    int col0 = nb * 64, row0 = ob * 128;
    int t = threadIdx.x;
    int l = t & 63, wid = t >> 6;
    int wr = wid >> 1, wc = wid & 1;
    int lr = l & 15, lg = l >> 4;
    const ushort* Ab = wkv16 + (size_t)row0 * 512;
    const float* Bb = cond + (size_t)b * 512 * 1024 + col0;
    int sp = t & 31, sj = t >> 5;
    int rA_ = t >> 3;
    int gA_ = (t & 7) ^ (rA_ & 7);      // (32j+rA_)&7 == rA_&7
    int rB = t >> 4, gB = t & 15;
    uint4 a0_, a1_, a2_, a3_;
    float4 b0_, b1_, b2_, b3_;          // B set 0
    float4 c0_, c1_, c2_, c3_;          // B set 1
#define KG_LOADA(k0) { \
    a0_ = *(const uint4*)(Ab + (size_t)(rA_)      * 512 + (k0) + gA_ * 8); \
    a1_ = *(const uint4*)(Ab + (size_t)(32 + rA_) * 512 + (k0) + gA_ * 8); \
    a2_ = *(const uint4*)(Ab + (size_t)(64 + rA_) * 512 + (k0) + gA_ * 8); \
    a3_ = *(const uint4*)(Ab + (size_t)(96 + rA_) * 512 + (k0) + gA_ * 8); }
#define KG_LOADB0(k0) { \
    b0_ = *(const float4*)&Bb[(size_t)((k0) + rB)      * 1024 + gB * 4]; \
    b1_ = *(const float4*)&Bb[(size_t)((k0) + 16 + rB) * 1024 + gB * 4]; \
    b2_ = *(const float4*)&Bb[(size_t)((k0) + 32 + rB) * 1024 + gB * 4]; \
    b3_ = *(const float4*)&Bb[(size_t)((k0) + 48 + rB) * 1024 + gB * 4]; }
#define KG_LOADB1(k0) { \
    c0_ = *(const float4*)&Bb[(size_t)((k0) + rB)      * 1024 + gB * 4]; \
    c1_ = *(const float4*)&Bb[(size_t)((k0) + 16 + rB) * 1024 + gB * 4]; \
    c2_ = *(const float4*)&Bb[(size_t)((k0) + 32 + rB) * 1024 + gB * 4]; \
    c3_ = *(const float4*)&Bb[(size_t)((k0) + 48 + rB) * 1024 + gB * 4]; }
#define KG_WRITEA() { \
    *(uint4*)((char*)lA + (size_t)(t) * 16)       = a0_; \
    *(uint4*)((char*)lA + (size_t)(256 + t) * 16) = a1_; \
    *(uint4*)((char*)lA + (size_t)(512 + t) * 16) = a2_; \
    *(uint4*)((char*)lA + (size_t)(768 + t) * 16) = a3_; }
#define KG_WRITEB(v0, v1, v2, v3) { \
    *(float4*)((char*)scratch + (rB)      * 256 + (gB ^ (((rB)      >> 1) & 15)) * 16) = v0; \
    *(float4*)((char*)scratch + (16 + rB) * 256 + (gB ^ (((16 + rB) >> 1) & 15)) * 16) = v1; \
    *(float4*)((char*)scratch + (32 + rB) * 256 + (gB ^ (((32 + rB) >> 1) & 15)) * 16) = v2; \
    *(float4*)((char*)scratch + (48 + rB) * 256 + (gB ^ (((48 + rB) >> 1) & 15)) * 16) = v3; }
#define KG_PACK() { \
    int swz = sp & 15; \
    float4 s0 = *(const float4*)((char*)scratch + (2*sp)   * 256 + ((2*sj)   ^ swz) * 16); \
    float4 s1 = *(const float4*)((char*)scratch + (2*sp)   * 256 + ((2*sj+1) ^ swz) * 16); \
    float4 s2 = *(const float4*)((char*)scratch + (2*sp+1) * 256 + ((2*sj)   ^ swz) * 16); \
    float4 s3 = *(const float4*)((char*)scratch + (2*sp+1) * 256 + ((2*sj+1) ^ swz) * 16); \
    float c0v[8] = {s0.x, s0.y, s0.z, s0.w, s1.x, s1.y, s1.z, s1.w}; \
    float c1v[8] = {s2.x, s2.y, s2.z, s2.w, s3.x, s3.y, s3.z, s3.w}; \
    _Pragma("unroll") \
    for (int w = 0; w < 8; ++w) { \
        int n = sj * 8 + w; \
        unsigned pk = (unsigned)f2bf(c0v[w]) | ((unsigned)f2bf(c1v[w]) << 16); \
        *(unsigned*)((char*)lB + n * 128 + (((sp >> 2) ^ (n & 7)) * 16) + (sp & 3) * 4) = pk; \
    } }
#define KG_MFMA() { \
    _Pragma("unroll") \
    for (int ks = 0; ks < 2; ++ks) { \
        bf16x8 av[4], bv[2]; \
        _Pragma("unroll") \
        for (int mi = 0; mi < 4; ++mi) { \
            int ar = wr * 64 + mi * 16 + lr; \
            int q = (ks * 4 + lg) ^ (ar & 7); \
            av[mi] = *(const bf16x8*)((const char*)lA + ar * 128 + q * 16); \
        } \
        _Pragma("unroll") \
        for (int ni = 0; ni < 2; ++ni) { \
            int br = wc * 32 + ni * 16 + lr; \
            int q = (ks * 4 + lg) ^ (br & 7); \
            bv[ni] = *(const bf16x8*)((const char*)lB + br * 128 + q * 16); \
        } \
        _Pragma("unroll") \
        for (int mi = 0; mi < 4; ++mi) \
            _Pragma("unroll") \
            for (int ni = 0; ni < 2; ++ni) \
                acc[mi][ni] = __builtin_amdgcn_mfma_f32_16x16x32_bf16( \
                    av[mi], bv[ni], acc[mi][ni], 0, 0, 0); \
    } }
    KG_LOADA(0); KG_LOADB0(0); KG_LOADB1(64);
    f32x4 acc[4][2] = {};
    #pragma unroll
    for (int ii = 0; ii < 4; ++ii) {
        int k0 = ii * 128;
        // even sub-iter (uses B set 0)
        KG_WRITEA();
        KG_WRITEB(b0_, b1_, b2_, b3_);
        __syncthreads();
        KG_LOADA(k0 + 64);                       // next A (1-deep)
        if (ii < 3) KG_LOADB0(k0 + 128);         // B set0 refill (2-deep)
        KG_PACK();
        __syncthreads();
        KG_MFMA();
        __syncthreads();
        // odd sub-iter (uses B set 1)
        KG_WRITEA();
        KG_WRITEB(c0_, c1_, c2_, c3_);
        __syncthreads();
        if (ii < 3) { KG_LOADA(k0 + 128); KG_LOADB1(k0 + 192); }
        KG_PACK();
        __syncthreads();
        KG_MFMA();
        __syncthreads();
    }
#undef KG_LOADA
#undef KG_LOADB0
#undef KG_LOADB1
#undef KG_WRITEA
#undef KG_WRITEB
#undef KG_PACK
#undef KG_MFMA
    int orow = row0 + wr * 64, ocol = col0 + wc * 32 + lr;
    #pragma unroll
    for (int mi = 0; mi < 4; ++mi) {
        int rb = orow + mi * 16 + lg * 4;
        float4 b4 = *(const float4*)&b_kv[rb];
        float bvr[4] = {b4.x, b4.y, b4.z, b4.w};
        #pragma unroll
        for (int ni = 0; ni < 2; ++ni) {
            int cc = ocol + ni * 16;
            #pragma unroll
            for (int r = 0; r < 4; ++r)
                kv16[((size_t)b * 256 + rb + r) * 1024 + cc] = f2bf(acc[mi][ni][r] + bvr[r]);
        }
    }
}

// ---------------------------------------------------------------------------
// L3: partial context, UNNORMALIZED: ctx[d,e] += sum_n exp(k[d,n]) v[e,n],
// rowsum[d] += sum_n exp(k[d,n]).  grid (8 nchunks, 64 bh).
__global__ __launch_bounds__(256) void ctx_partial_kernel(const ushort* __restrict__ kv,
                                                          float* __restrict__ rowsum,
                                                          float* __restrict__ ctx) {
    int bh = blockIdx.y, b = bh >> 2, h = bh & 3;
    int n0 = blockIdx.x * 128;
    __shared__ float pl[32][129], vl[32][129];
    int t = threadIdx.x;
    int r = t >> 3, cs = (t & 7) * 16;
    const ushort* kp = kv + ((size_t)b * 256 + h * 32 + r) * 1024 + n0 + cs;
    const ushort* vp = kv + ((size_t)b * 256 + 128 + h * 32 + r) * 1024 + n0 + cs;
    float kvals[16], vvals[16];
    unpack8(((const uint4*)kp)[0], kvals);
    unpack8(((const uint4*)kp)[1], kvals + 8);
    unpack8(((const uint4*)vp)[0], vvals);
    unpack8(((const uint4*)vp)[1], vvals + 8);
    float psum = 0.f;
    #pragma unroll
    for (int i = 0; i < 16; ++i) {
        float e = __expf(kvals[i]);
        pl[r][cs + i] = e;
        vl[r][cs + i] = vvals[i];
        psum += e;
    }
    psum += __shfl_xor(psum, 1, 64);
    psum += __shfl_xor(psum, 2, 64);
    psum += __shfl_xor(psum, 4, 64);
    if ((t & 7) == 0) atomicAdd(&rowsum[bh * 32 + r], psum);
    __syncthreads();
    int d0 = t >> 5, e0 = t & 31;
    float acc[4] = {0.f, 0.f, 0.f, 0.f};
    #pragma unroll 8
    for (int nn = 0; nn < 128; ++nn) {
        float vv = vl[e0][nn];
        #pragma unroll
        for (int i = 0; i < 4; ++i)
            acc[i] += pl[d0 + 8 * i][nn] * vv;
    }
    #pragma unroll
    for (int i = 0; i < 4; ++i)
        atomicAdd(&ctx[((size_t)bh * 32 + d0 + 8 * i) * 32 + e0], acc[i]);
}

// ---------------------------------------------------------------------------
// L4: A-fold: normalize ctx by rowsum, M = w_out@ctx^T in LDS, then
// A16[b,o,c] = bf16(wt*s), biasb[b,o] = sum_c wt*t + M.b_q + b_out
__global__ __launch_bounds__(256) void a_kernel(const float* __restrict__ ctx,
                                                const float* __restrict__ rowsum,
                                                const float* __restrict__ w_out,
                                                const float* __restrict__ w_q,
                                                const float* __restrict__ b_q,
                                                const float* __restrict__ statacc,
                                                const float* __restrict__ gn_w,
                                                const float* __restrict__ gn_b,
                                                const float* __restrict__ b_out,
                                                ushort* __restrict__ A16,
                                                float* __restrict__ biasb) {
    __shared__ float ctxl[4][32][33];
    __shared__ float wol[16][128];
    __shared__ float ml[16][128];
    __shared__ float cbuf[256][17];
    __shared__ float pbuf[16][17];
    int b = blockIdx.x >> 4, ot = (blockIdx.x & 15) << 4;
    int t = threadIdx.x;
    #pragma unroll
    for (int j = 0; j < 16; ++j) {
        int e = t + 256 * j;            // 0..4095
        float inv = 1.f / rowsum[b * 128 + (e >> 5)];
        ctxl[e >> 10][(e >> 5) & 31][e & 31] = ctx[(size_t)b * 4096 + e] * inv;
    }
    #pragma unroll
    for (int j = 0; j < 8; ++j) {
        int e = t + 256 * j;            // 0..2047
        wol[e >> 7][e & 127] = w_out[(ot + (e >> 7)) * 128 + (e & 127)];
    }
    __syncthreads();
    #pragma unroll
    for (int j = 0; j < 8; ++j) {
        int e = t + 256 * j;
        int o = e >> 7, hd = e & 127, h = hd >> 5, d = hd & 31;
        float acc = 0.f;
        #pragma unroll
        for (int ee = 0; ee < 32; ++ee) acc += wol[o][h * 32 + ee] * ctxl[h][d][ee];
        ml[o][hd] = acc;
    }
    __syncthreads();
    int c = t, g = c >> 3;
    float a0 = statacc[(b * 32 + g) * 2], a1 = statacc[(b * 32 + g) * 2 + 1];
    float mu  = a0 * (1.f / 32768.f);
    float var = a1 * (1.f / 32768.f) - mu * mu;
    float sc = rsqrtf(var + 1e-5f) * gn_w[c];
    float tc = gn_b[c] - mu * sc;
    float wt[16];
    #pragma unroll
    for (int o = 0; o < 16; ++o) wt[o] = 0.f;
    for (int hd = 0; hd < 128; ++hd) {
        float wq = w_q[hd * 256 + c];
        #pragma unroll
        for (int o = 0; o < 16; ++o) wt[o] += ml[o][hd] * wq;
    }
    ushort* Abp = A16 + ((size_t)b * 256 + ot) * 256 + c;
    #pragma unroll
    for (int o = 0; o < 16; ++o) {
        Abp[(size_t)o * 256] = f2bf(wt[o] * sc);
        cbuf[c][o] = wt[o] * tc;
    }
    __syncthreads();
    {
        int o = t >> 4, seg = t & 15;
        float p = 0.f;
        #pragma unroll
        for (int i = 0; i < 16; ++i) p += cbuf[seg * 16 + i][o];
        pbuf[o][seg] = p;
    }
    __syncthreads();
    if (t < 16) {
        int o = t;
        float sum = 0.f;
        #pragma unroll
        for (int s2 = 0; s2 < 16; ++s2) sum += pbuf[o][s2];
        float md = 0.f;
        #pragma unroll 8
        for (int hd = 0; hd < 128; ++hd) md += ml[o][hd] * b_q[hd];
        biasb[(size_t)b * 256 + ot + o] = sum + md + b_out[ot + o];
    }
}

// ---------------------------------------------------------------------------
// L5: out = A16 @ x^T + bias.  BM=256, BN=128, BK=64; 8 waves (4x2), 512 thr.
// A and B reg-staged via NAMED regs with next-tile prefetch.
__global__ __launch_bounds__(512) void out_gemm_fused(const ushort* __restrict__ A16,
                                                      const float* __restrict__ x,
                                                      const float* __restrict__ biasb,
                                                      float* __restrict__ out) {
    __shared__ ushort lA[256 * 64];     // 32 KB
    __shared__ ushort lB[128 * 64];     // 16 KB
    __shared__ float scratch[64 * 128]; // 32 KB, granule-swizzled
    int b = blockIdx.y;
    int n0 = blockIdx.x * 128;
    int t = threadIdx.x;
    int l = t & 63, wid = t >> 6;
    int wr = wid >> 1, wc = wid & 1;          // 4 x 2 wave grid
    int lr = l & 15, lg = l >> 4;
    const ushort* Ab = A16 + (size_t)b * 65536;
    const float* xb = x + (size_t)b * 256 * 4096 + n0;
    int sp = t & 31, sj = t >> 5;             // c-pair (2sp,2sp+1), n-octet (16)
    uint4 a0_, a1_, a2_, a3_;
    float4 b0_, b1_, b2_, b3_;
    int rA = t >> 3, gA = (t & 7) ^ (rA & 7); // (64k+rA)&7 == rA&7
    int rB = t >> 5, gB = t & 31;
#define OG_LOADA(k0) { \
    a0_ = *(const uint4*)(Ab + (size_t)(rA)       * 256 + (k0) + gA * 8); \
    a1_ = *(const uint4*)(Ab + (size_t)(64 + rA)  * 256 + (k0) + gA * 8); \
    a2_ = *(const uint4*)(Ab + (size_t)(128 + rA) * 256 + (k0) + gA * 8); \
    a3_ = *(const uint4*)(Ab + (size_t)(192 + rA) * 256 + (k0) + gA * 8); }
#define OG_LOADB(k0) { \
    b0_ = *(const float4*)&xb[(size_t)((k0) + rB)      * 4096 + gB * 4]; \
    b1_ = *(const float4*)&xb[(size_t)((k0) + 16 + rB) * 4096 + gB * 4]; \
    b2_ = *(const float4*)&xb[(size_t)((k0) + 32 + rB) * 4096 + gB * 4]; \
    b3_ = *(const float4*)&xb[(size_t)((k0) + 48 + rB) * 4096 + gB * 4]; }
    OG_LOADA(0); OG_LOADB(0);
    f32x4 acc[4][4] = {};
    for (int it = 0; it < 4; ++it) {
        *(uint4*)((char*)lA + (size_t)t * 16)          = a0_;
        *(uint4*)((char*)lA + (size_t)(512 + t) * 16)  = a1_;
        *(uint4*)((char*)lA + (size_t)(1024 + t) * 16) = a2_;
        *(uint4*)((char*)lA + (size_t)(1536 + t) * 16) = a3_;
        *(float4*)((char*)scratch + (rB)      * 512 + (gB ^ (((rB)      >> 1) & 31)) * 16) = b0_;
        *(float4*)((char*)scratch + (16 + rB) * 512 + (gB ^ (((16 + rB) >> 1) & 31)) * 16) = b1_;
        *(float4*)((char*)scratch + (32 + rB) * 512 + (gB ^ (((32 + rB) >> 1) & 31)) * 16) = b2_;
        *(float4*)((char*)scratch + (48 + rB) * 512 + (gB ^ (((48 + rB) >> 1) & 31)) * 16) = b3_;
        __syncthreads();
        if (it < 3) { OG_LOADA(it * 64 + 64); OG_LOADB(it * 64 + 64); }   // prefetch
        {
            int swz = sp & 31;
            float4 s0 = *(const float4*)((char*)scratch + (2*sp)   * 512 + ((2*sj)   ^ swz) * 16);
            float4 s1 = *(const float4*)((char*)scratch + (2*sp)   * 512 + ((2*sj+1) ^ swz) * 16);
            float4 s2 = *(const float4*)((char*)scratch + (2*sp+1) * 512 + ((2*sj)   ^ swz) * 16);
            float4 s3 = *(const float4*)((char*)scratch + (2*sp+1) * 512 + ((2*sj+1) ^ swz) * 16);
            float c0v[8] = {s0.x, s0.y, s0.z, s0.w, s1.x, s1.y, s1.z, s1.w};
            float c1v[8] = {s2.x, s2.y, s2.z, s2.w, s3.x, s3.y, s3.z, s3.w};
            #pragma unroll
            for (int w = 0; w < 8; ++w) {
                int n = sj * 8 + w;
                unsigned pk = (unsigned)f2bf(c0v[w]) | ((unsigned)f2bf(c1v[w]) << 16);
                *(unsigned*)((char*)lB + n * 128 + (((sp >> 2) ^ (n & 7)) * 16) + (sp & 3) * 4) = pk;
            }
        }
        __syncthreads();
        #pragma unroll
        for (int ks = 0; ks < 2; ++ks) {
            bf16x8 av[4], bv[4];
            #pragma unroll
            for (int mi = 0; mi < 4; ++mi) {
                int ar = wr * 64 + mi * 16 + lr;
                int q = (ks * 4 + lg) ^ (ar & 7);
                av[mi] = *(const bf16x8*)((const char*)lA + ar * 128 + q * 16);
            }
            #pragma unroll
            for (int ni = 0; ni < 4; ++ni) {
                int br = wc * 64 + ni * 16 + lr;
                int q = (ks * 4 + lg) ^ (br & 7);
                bv[ni] = *(const bf16x8*)((const char*)lB + br * 128 + q * 16);
            }
            #pragma unroll
            for (int mi = 0; mi < 4; ++mi)
                #pragma unroll
                for (int ni = 0; ni < 4; ++ni)
                    acc[mi][ni] = __builtin_amdgcn_mfma_f32_16x16x32_bf16(
                        av[mi], bv[ni], acc[mi][ni], 0, 0, 0);
        }
        __syncthreads();
    }
#undef OG_LOADA
#undef OG_LOADB
    const float* bp = biasb + (size_t)b * 256;
    int orow = wr * 64, ocol = n0 + wc * 64 + lr;
    #pragma unroll
    for (int mi = 0; mi < 4; ++mi) {
        int rb = orow + mi * 16 + lg * 4;
        float4 b4 = *(const float4*)&bp[rb];
        float bvr[4] = {b4.x, b4.y, b4.z, b4.w};
        #pragma unroll
        for (int ni = 0; ni < 4; ++ni) {
            int cc = ocol + ni * 16;
            #pragma unroll
            for (int r = 0; r < 4; ++r)
                out[((size_t)b * 256 + rb + r) * 4096 + cc] = acc[mi][ni][r] + bvr[r];
        }
    }
}

extern "C" void kernel_launch(void* const* d_in, const int* in_sizes, int n_in,
                              void* d_out, int out_size, void* d_ws, size_t ws_size,
                              hipStream_t stream) {
    const float* x     = (const float*)d_in[0];
    const float* cond  = (const float*)d_in[1];
    const float* gn_w  = (const float*)d_in[2];
    const float* gn_b  = (const float*)d_in[3];
    const float* w_q   = (const float*)d_in[4];
    const float* b_q   = (const float*)d_in[5];
    const float* w_kv  = (const float*)d_in[6];
    const float* b_kv  = (const float*)d_in[7];
    const float* w_out = (const float*)d_in[8];
    const float* b_out = (const float*)d_in[9];
    float* out = (float*)d_out;

    float* f       = (float*)d_ws;
    float* statacc = f;                     // 1024 floats (plain stores, no zero)
    float* rowsum  = f + 1024;              // 2048 floats (zeroed in prep)
    float* ctx     = f + 3072;              // 65536 floats (zeroed in prep)
    float* biasb   = f + 68608;             // 4096 floats
    ushort* u      = (ushort*)(f + 72704);
    ushort* wkv16  = u;                     // 131072
    ushort* kv16   = u + 131072;            // 4194304
    ushort* A16    = u + 4325376;           // 1048576

    // L1: w_kv convert + zero rowsum/ctx + GN stats (one block per (b,g))
    prep_kernel<<<1024, 256, 0, stream>>>(w_kv, wkv16, rowsum, x, statacc);
    // L2: kv GEMM (BM=128, 2-deep B prefetch)
    kv_gemm<<<dim3(16, 2, 16), 256, 0, stream>>>(wkv16, cond, b_kv, kv16);
    // L3: unnormalized context + row sums
    ctx_partial_kernel<<<dim3(8, 64), 256, 0, stream>>>(kv16, rowsum, ctx);
    // L4: fold everything into per-batch A (bf16) + bias
    a_kernel<<<256, 256, 0, stream>>>(ctx, rowsum, w_out, w_q, b_q, statacc,
                                      gn_w, gn_b, b_out, A16, biasb);
    // L5: out = A @ x^T + bias
    out_gemm_fused<<<dim3(32, 16), 512, 0, stream>>>(A16, x, biasb, out);
}

// Round 13
// 80.675 us; speedup vs baseline: 1.8813x; 1.0425x over previous
//
#include <hip/hip_runtime.h>
#include <hip/hip_bf16.h>

typedef __attribute__((ext_vector_type(8))) short bf16x8;
typedef __attribute__((ext_vector_type(4))) float f32x4;

__device__ __forceinline__ ushort f2bf(float f) {
    __hip_bfloat16 h = __float2bfloat16(f);
    return __builtin_bit_cast(ushort, h);
}
__device__ __forceinline__ unsigned pack2(float a, float b) {
    return (unsigned)f2bf(a) | ((unsigned)f2bf(b) << 16);
}
__device__ __forceinline__ float bflo(unsigned u) { return __uint_as_float(u << 16); }
__device__ __forceinline__ float bfhi(unsigned u) { return __uint_as_float(u & 0xffff0000u); }

__device__ __forceinline__ void unpack8(uint4 r, float* o) {
    o[0] = bflo(r.x); o[1] = bfhi(r.x); o[2] = bflo(r.y); o[3] = bfhi(r.y);
    o[4] = bflo(r.z); o[5] = bfhi(r.z); o[6] = bflo(r.w); o[7] = bfhi(r.w);
}

// ---------------------------------------------------------------------------
// L1 merged: blocks [0,512): kv = w_kv @ cond. BM=128, BN=64, BK=64, K=512.
//   BOTH operands read as fp32 and converted in LDS staging (w_kv rows are
//   K-contiguous: coalesced, no transpose; cond goes via swizzled scratch).
//   blocks [512,1024): zero rowsum/ctx + GroupNorm sums (one block per (b,g)).
__global__ __launch_bounds__(256) void kvprep_kernel(const float* __restrict__ w_kv,
                                                     const float* __restrict__ cond,
                                                     const float* __restrict__ b_kv,
                                                     ushort* __restrict__ kv16,
                                                     const float* __restrict__ x,
                                                     float* __restrict__ statacc,
                                                     float* __restrict__ zbase) {
    __shared__ ushort lA[128 * 64];     // 16 KB
    __shared__ ushort lB[64 * 64];      // 8 KB
    __shared__ float scratch[64 * 64];  // 16 KB, granule-swizzled
    __shared__ float red[8];
    int bid = blockIdx.x, t = threadIdx.x;
    if (bid < 512) {
        int nb = bid & 15, ob = (bid >> 4) & 1, b = bid >> 5;
        int col0 = nb * 64, row0 = ob * 128;
        int l = t & 63, wid = t >> 6;
        int wr = wid >> 1, wc = wid & 1;
        int lr = l & 15, lg = l >> 4;
        const float* Ab32 = w_kv + (size_t)row0 * 512;
        const float* Bb = cond + (size_t)b * 512 * 1024 + col0;
        int sp = t & 31, sj = t >> 5;
        int rA = t >> 3, gAr = t & 7, gw = gAr ^ (rA & 7);  // (32j+rA)&7==rA&7
        int rB = t >> 4, gB = t & 15;
        // named staging regs (rule #20: no arrays)
        float4 ka0_, ka1_, ka2_, ka3_, ka4_, ka5_, ka6_, ka7_;
        float4 kb0_, kb1_, kb2_, kb3_;
#define KP_LOADA(k0) { \
    ka0_ = *(const float4*)&Ab32[(size_t)(rA)      * 512 + (k0) + gAr * 8]; \
    ka1_ = *(const float4*)&Ab32[(size_t)(rA)      * 512 + (k0) + gAr * 8 + 4]; \
    ka2_ = *(const float4*)&Ab32[(size_t)(32 + rA) * 512 + (k0) + gAr * 8]; \
    ka3_ = *(const float4*)&Ab32[(size_t)(32 + rA) * 512 + (k0) + gAr * 8 + 4]; \
    ka4_ = *(const float4*)&Ab32[(size_t)(64 + rA) * 512 + (k0) + gAr * 8]; \
    ka5_ = *(const float4*)&Ab32[(size_t)(64 + rA) * 512 + (k0) + gAr * 8 + 4]; \
    ka6_ = *(const float4*)&Ab32[(size_t)(96 + rA) * 512 + (k0) + gAr * 8]; \
    ka7_ = *(const float4*)&Ab32[(size_t)(96 + rA) * 512 + (k0) + gAr * 8 + 4]; }
#define KP_LOADB(k0) { \
    kb0_ = *(const float4*)&Bb[(size_t)((k0) + rB)      * 1024 + gB * 4]; \
    kb1_ = *(const float4*)&Bb[(size_t)((k0) + 16 + rB) * 1024 + gB * 4]; \
    kb2_ = *(const float4*)&Bb[(size_t)((k0) + 32 + rB) * 1024 + gB * 4]; \
    kb3_ = *(const float4*)&Bb[(size_t)((k0) + 48 + rB) * 1024 + gB * 4]; }
#define KP_WRITEA() { \
    uint4 p; \
    p.x = pack2(ka0_.x, ka0_.y); p.y = pack2(ka0_.z, ka0_.w); \
    p.z = pack2(ka1_.x, ka1_.y); p.w = pack2(ka1_.z, ka1_.w); \
    *(uint4*)((char*)lA + (size_t)((rA)      * 8 + gw) * 16) = p; \
    p.x = pack2(ka2_.x, ka2_.y); p.y = pack2(ka2_.z, ka2_.w); \
    p.z = pack2(ka3_.x, ka3_.y); p.w = pack2(ka3_.z, ka3_.w); \
    *(uint4*)((char*)lA + (size_t)((32 + rA) * 8 + gw) * 16) = p; \
    p.x = pack2(ka4_.x, ka4_.y); p.y = pack2(ka4_.z, ka4_.w); \
    p.z = pack2(ka5_.x, ka5_.y); p.w = pack2(ka5_.z, ka5_.w); \
    *(uint4*)((char*)lA + (size_t)((64 + rA) * 8 + gw) * 16) = p; \
    p.x = pack2(ka6_.x, ka6_.y); p.y = pack2(ka6_.z, ka6_.w); \
    p.z = pack2(ka7_.x, ka7_.y); p.w = pack2(ka7_.z, ka7_.w); \
    *(uint4*)((char*)lA + (size_t)((96 + rA) * 8 + gw) * 16) = p; }
#define KP_WRITEB() { \
    *(float4*)((char*)scratch + (rB)      * 256 + (gB ^ (((rB)      >> 1) & 15)) * 16) = kb0_; \
    *(float4*)((char*)scratch + (16 + rB) * 256 + (gB ^ (((16 + rB) >> 1) & 15)) * 16) = kb1_; \
    *(float4*)((char*)scratch + (32 + rB) * 256 + (gB ^ (((32 + rB) >> 1) & 15)) * 16) = kb2_; \
    *(float4*)((char*)scratch + (48 + rB) * 256 + (gB ^ (((48 + rB) >> 1) & 15)) * 16) = kb3_; }
#define KP_PACKB() { \
    int swz = sp & 15; \
    float4 s0 = *(const float4*)((char*)scratch + (2*sp)   * 256 + ((2*sj)   ^ swz) * 16); \
    float4 s1 = *(const float4*)((char*)scratch + (2*sp)   * 256 + ((2*sj+1) ^ swz) * 16); \
    float4 s2 = *(const float4*)((char*)scratch + (2*sp+1) * 256 + ((2*sj)   ^ swz) * 16); \
    float4 s3 = *(const float4*)((char*)scratch + (2*sp+1) * 256 + ((2*sj+1) ^ swz) * 16); \
    float c0v[8] = {s0.x, s0.y, s0.z, s0.w, s1.x, s1.y, s1.z, s1.w}; \
    float c1v[8] = {s2.x, s2.y, s2.z, s2.w, s3.x, s3.y, s3.z, s3.w}; \
    _Pragma("unroll") \
    for (int w = 0; w < 8; ++w) { \
        int n = sj * 8 + w; \
        unsigned pk = pack2(c0v[w], c1v[w]); \
        *(unsigned*)((char*)lB + n * 128 + (((sp >> 2) ^ (n & 7)) * 16) + (sp & 3) * 4) = pk; \
    } }
        KP_LOADA(0); KP_LOADB(0);
        f32x4 acc[4][2] = {};
        for (int it = 0; it < 8; ++it) {
            KP_WRITEA();
            KP_WRITEB();
            __syncthreads();
            if (it < 7) { KP_LOADA(it * 64 + 64); KP_LOADB(it * 64 + 64); }  // prefetch
            KP_PACKB();
            __syncthreads();
            #pragma unroll
            for (int ks = 0; ks < 2; ++ks) {
                bf16x8 av[4], bv[2];
                #pragma unroll
                for (int mi = 0; mi < 4; ++mi) {
                    int ar = wr * 64 + mi * 16 + lr;
                    int q = (ks * 4 + lg) ^ (ar & 7);
                    av[mi] = *(const bf16x8*)((const char*)lA + ar * 128 + q * 16);
                }
                #pragma unroll
                for (int ni = 0; ni < 2; ++ni) {
                    int br = wc * 32 + ni * 16 + lr;
                    int q = (ks * 4 + lg) ^ (br & 7);
                    bv[ni] = *(const bf16x8*)((const char*)lB + br * 128 + q * 16);
                }
                #pragma unroll
                for (int mi = 0; mi < 4; ++mi)
                    #pragma unroll
                    for (int ni = 0; ni < 2; ++ni)
                        acc[mi][ni] = __builtin_amdgcn_mfma_f32_16x16x32_bf16(
                            av[mi], bv[ni], acc[mi][ni], 0, 0, 0);
            }
            __syncthreads();
        }
#undef KP_LOADA
#undef KP_LOADB
#undef KP_WRITEA
#undef KP_WRITEB
#undef KP_PACKB
        int orow = row0 + wr * 64, ocol = col0 + wc * 32 + lr;
        #pragma unroll
        for (int mi = 0; mi < 4; ++mi) {
            int rb = orow + mi * 16 + lg * 4;
            float4 b4 = *(const float4*)&b_kv[rb];
            float bvr[4] = {b4.x, b4.y, b4.z, b4.w};
            #pragma unroll
            for (int ni = 0; ni < 2; ++ni) {
                int cc = ocol + ni * 16;
                #pragma unroll
                for (int r = 0; r < 4; ++r)
                    kv16[((size_t)b * 256 + rb + r) * 1024 + cc] = f2bf(acc[mi][ni][r] + bvr[r]);
            }
        }
    } else {
        int bg = bid - 512;              // 0..511 = (b,g)
        int zi = bg * 256 + t;
        if (zi < 67584) zbase[zi] = 0.f; // rowsum (2048) + ctx (65536)
        const float4* xp = (const float4*)(x + (size_t)bg * 32768);
        float s = 0.f, ss = 0.f;
        #pragma unroll
        for (int j = 0; j < 32; ++j) {
            float4 v = xp[t + 256 * j];
            s  += v.x + v.y + v.z + v.w;
            ss += v.x*v.x + v.y*v.y + v.z*v.z + v.w*v.w;
        }
        #pragma unroll
        for (int off = 32; off > 0; off >>= 1) {
            s  += __shfl_down(s, off, 64);
            ss += __shfl_down(ss, off, 64);
        }
        int wave = t >> 6;
        if ((t & 63) == 0) { red[wave * 2] = s; red[wave * 2 + 1] = ss; }
        __syncthreads();
        if (t == 0) {
            statacc[bg * 2]     = red[0] + red[2] + red[4] + red[6];
            statacc[bg * 2 + 1] = red[1] + red[3] + red[5] + red[7];
        }
    }
}

// ---------------------------------------------------------------------------
// L2: partial context, UNNORMALIZED: ctx[d,e] += sum_n exp(k[d,n]) v[e,n],
// rowsum[d] += sum_n exp(k[d,n]).  grid (8 nchunks, 64 bh).
__global__ __launch_bounds__(256) void ctx_partial_kernel(const ushort* __restrict__ kv,
                                                          float* __restrict__ rowsum,
                                                          float* __restrict__ ctx) {
    int bh = blockIdx.y, b = bh >> 2, h = bh & 3;
    int n0 = blockIdx.x * 128;
    __shared__ float pl[32][129], vl[32][129];
    int t = threadIdx.x;
    int r = t >> 3, cs = (t & 7) * 16;
    const ushort* kp = kv + ((size_t)b * 256 + h * 32 + r) * 1024 + n0 + cs;
    const ushort* vp = kv + ((size_t)b * 256 + 128 + h * 32 + r) * 1024 + n0 + cs;
    float kvals[16], vvals[16];
    unpack8(((const uint4*)kp)[0], kvals);
    unpack8(((const uint4*)kp)[1], kvals + 8);
    unpack8(((const uint4*)vp)[0], vvals);
    unpack8(((const uint4*)vp)[1], vvals + 8);
    float psum = 0.f;
    #pragma unroll
    for (int i = 0; i < 16; ++i) {
        float e = __expf(kvals[i]);
        pl[r][cs + i] = e;
        vl[r][cs + i] = vvals[i];
        psum += e;
    }
    psum += __shfl_xor(psum, 1, 64);
    psum += __shfl_xor(psum, 2, 64);
    psum += __shfl_xor(psum, 4, 64);
    if ((t & 7) == 0) atomicAdd(&rowsum[bh * 32 + r], psum);
    __syncthreads();
    int d0 = t >> 5, e0 = t & 31;
    float acc[4] = {0.f, 0.f, 0.f, 0.f};
    #pragma unroll 8
    for (int nn = 0; nn < 128; ++nn) {
        float vv = vl[e0][nn];
        #pragma unroll
        for (int i = 0; i < 4; ++i)
            acc[i] += pl[d0 + 8 * i][nn] * vv;
    }
    #pragma unroll
    for (int i = 0; i < 4; ++i)
        atomicAdd(&ctx[((size_t)bh * 32 + d0 + 8 * i) * 32 + e0], acc[i]);
}

// ---------------------------------------------------------------------------
// L3: A-fold: normalize ctx by rowsum, M = w_out@ctx^T in LDS, then
// A16[b,o,c] = bf16(wt*s), biasb[b,o] = sum_c wt*t + M.b_q + b_out
__global__ __launch_bounds__(256) void a_kernel(const float* __restrict__ ctx,
                                                const float* __restrict__ rowsum,
                                                const float* __restrict__ w_out,
                                                const float* __restrict__ w_q,
                                                const float* __restrict__ b_q,
                                                const float* __restrict__ statacc,
                                                const float* __restrict__ gn_w,
                                                const float* __restrict__ gn_b,
                                                const float* __restrict__ b_out,
                                                ushort* __restrict__ A16,
                                                float* __restrict__ biasb) {
    __shared__ float ctxl[4][32][33];
    __shared__ float wol[16][128];
    __shared__ float ml[16][128];
    __shared__ float cbuf[256][17];
    __shared__ float pbuf[16][17];
    int b = blockIdx.x >> 4, ot = (blockIdx.x & 15) << 4;
    int t = threadIdx.x;
    #pragma unroll
    for (int j = 0; j < 16; ++j) {
        int e = t + 256 * j;            // 0..4095
        float inv = 1.f / rowsum[b * 128 + (e >> 5)];
        ctxl[e >> 10][(e >> 5) & 31][e & 31] = ctx[(size_t)b * 4096 + e] * inv;
    }
    #pragma unroll
    for (int j = 0; j < 8; ++j) {
        int e = t + 256 * j;            // 0..2047
        wol[e >> 7][e & 127] = w_out[(ot + (e >> 7)) * 128 + (e & 127)];
    }
    __syncthreads();
    #pragma unroll
    for (int j = 0; j < 8; ++j) {
        int e = t + 256 * j;
        int o = e >> 7, hd = e & 127, h = hd >> 5, d = hd & 31;
        float acc = 0.f;
        #pragma unroll
        for (int ee = 0; ee < 32; ++ee) acc += wol[o][h * 32 + ee] * ctxl[h][d][ee];
        ml[o][hd] = acc;
    }
    __syncthreads();
    int c = t, g = c >> 3;
    float a0 = statacc[(b * 32 + g) * 2], a1 = statacc[(b * 32 + g) * 2 + 1];
    float mu  = a0 * (1.f / 32768.f);
    float var = a1 * (1.f / 32768.f) - mu * mu;
    float sc = rsqrtf(var + 1e-5f) * gn_w[c];
    float tc = gn_b[c] - mu * sc;
    float wt[16];
    #pragma unroll
    for (int o = 0; o < 16; ++o) wt[o] = 0.f;
    for (int hd = 0; hd < 128; ++hd) {
        float wq = w_q[hd * 256 + c];
        #pragma unroll
        for (int o = 0; o < 16; ++o) wt[o] += ml[o][hd] * wq;
    }
    ushort* Abp = A16 + ((size_t)b * 256 + ot) * 256 + c;
    #pragma unroll
    for (int o = 0; o < 16; ++o) {
        Abp[(size_t)o * 256] = f2bf(wt[o] * sc);
        cbuf[c][o] = wt[o] * tc;
    }
    __syncthreads();
    {
        int o = t >> 4, seg = t & 15;
        float p = 0.f;
        #pragma unroll
        for (int i = 0; i < 16; ++i) p += cbuf[seg * 16 + i][o];
        pbuf[o][seg] = p;
    }
    __syncthreads();
    if (t < 16) {
        int o = t;
        float sum = 0.f;
        #pragma unroll
        for (int s2 = 0; s2 < 16; ++s2) sum += pbuf[o][s2];
        float md = 0.f;
        #pragma unroll 8
        for (int hd = 0; hd < 128; ++hd) md += ml[o][hd] * b_q[hd];
        biasb[(size_t)b * 256 + ot + o] = sum + md + b_out[ot + o];
    }
}

// ---------------------------------------------------------------------------
// L4: out = A16 @ x^T + bias.  BM=256, BN=128, BK=64; 8 waves (4x2), 512 thr.
// A and B reg-staged via NAMED regs with next-tile prefetch.
__global__ __launch_bounds__(512) void out_gemm_fused(const ushort* __restrict__ A16,
                                                      const float* __restrict__ x,
                                                      const float* __restrict__ biasb,
                                                      float* __restrict__ out) {
    __shared__ ushort lA[256 * 64];     // 32 KB
    __shared__ ushort lB[128 * 64];     // 16 KB
    __shared__ float scratch[64 * 128]; // 32 KB, granule-swizzled
    int b = blockIdx.y;
    int n0 = blockIdx.x * 128;
    int t = threadIdx.x;
    int l = t & 63, wid = t >> 6;
    int wr = wid >> 1, wc = wid & 1;          // 4 x 2 wave grid
    int lr = l & 15, lg = l >> 4;
    const ushort* Ab = A16 + (size_t)b * 65536;
    const float* xb = x + (size_t)b * 256 * 4096 + n0;
    int sp = t & 31, sj = t >> 5;             // c-pair (2sp,2sp+1), n-octet (16)
    uint4 a0_, a1_, a2_, a3_;
    float4 b0_, b1_, b2_, b3_;
    int rA = t >> 3, gA = (t & 7) ^ (rA & 7); // (64k+rA)&7 == rA&7
    int rB = t >> 5, gB = t & 31;
#define OG_LOADA(k0) { \
    a0_ = *(const uint4*)(Ab + (size_t)(rA)       * 256 + (k0) + gA * 8); \
    a1_ = *(const uint4*)(Ab + (size_t)(64 + rA)  * 256 + (k0) + gA * 8); \
    a2_ = *(const uint4*)(Ab + (size_t)(128 + rA) * 256 + (k0) + gA * 8); \
    a3_ = *(const uint4*)(Ab + (size_t)(192 + rA) * 256 + (k0) + gA * 8); }
#define OG_LOADB(k0) { \
    b0_ = *(const float4*)&xb[(size_t)((k0) + rB)      * 4096 + gB * 4]; \
    b1_ = *(const float4*)&xb[(size_t)((k0) + 16 + rB) * 4096 + gB * 4]; \
    b2_ = *(const float4*)&xb[(size_t)((k0) + 32 + rB) * 4096 + gB * 4]; \
    b3_ = *(const float4*)&xb[(size_t)((k0) + 48 + rB) * 4096 + gB * 4]; }
    OG_LOADA(0); OG_LOADB(0);
    f32x4 acc[4][4] = {};
    for (int it = 0; it < 4; ++it) {
        *(uint4*)((char*)lA + (size_t)t * 16)          = a0_;
        *(uint4*)((char*)lA + (size_t)(512 + t) * 16)  = a1_;
        *(uint4*)((char*)lA + (size_t)(1024 + t) * 16) = a2_;
        *(uint4*)((char*)lA + (size_t)(1536 + t) * 16) = a3_;
        *(float4*)((char*)scratch + (rB)      * 512 + (gB ^ (((rB)      >> 1) & 31)) * 16) = b0_;
        *(float4*)((char*)scratch + (16 + rB) * 512 + (gB ^ (((16 + rB) >> 1) & 31)) * 16) = b1_;
        *(float4*)((char*)scratch + (32 + rB) * 512 + (gB ^ (((32 + rB) >> 1) & 31)) * 16) = b2_;
        *(float4*)((char*)scratch + (48 + rB) * 512 + (gB ^ (((48 + rB) >> 1) & 31)) * 16) = b3_;
        __syncthreads();
        if (it < 3) { OG_LOADA(it * 64 + 64); OG_LOADB(it * 64 + 64); }   // prefetch
        {
            int swz = sp & 31;
            float4 s0 = *(const float4*)((char*)scratch + (2*sp)   * 512 + ((2*sj)   ^ swz) * 16);
            float4 s1 = *(const float4*)((char*)scratch + (2*sp)   * 512 + ((2*sj+1) ^ swz) * 16);
            float4 s2 = *(const float4*)((char*)scratch + (2*sp+1) * 512 + ((2*sj)   ^ swz) * 16);
            float4 s3 = *(const float4*)((char*)scratch + (2*sp+1) * 512 + ((2*sj+1) ^ swz) * 16);
            float c0v[8] = {s0.x, s0.y, s0.z, s0.w, s1.x, s1.y, s1.z, s1.w};
            float c1v[8] = {s2.x, s2.y, s2.z, s2.w, s3.x, s3.y, s3.z, s3.w};
            #pragma unroll
            for (int w = 0; w < 8; ++w) {
                int n = sj * 8 + w;
                unsigned pk = pack2(c0v[w], c1v[w]);
                *(unsigned*)((char*)lB + n * 128 + (((sp >> 2) ^ (n & 7)) * 16) + (sp & 3) * 4) = pk;
            }
        }
        __syncthreads();
        #pragma unroll
        for (int ks = 0; ks < 2; ++ks) {
            bf16x8 av[4], bv[4];
            #pragma unroll
            for (int mi = 0; mi < 4; ++mi) {
                int ar = wr * 64 + mi * 16 + lr;
                int q = (ks * 4 + lg) ^ (ar & 7);
                av[mi] = *(const bf16x8*)((const char*)lA + ar * 128 + q * 16);
            }
            #pragma unroll
            for (int ni = 0; ni < 4; ++ni) {
                int br = wc * 64 + ni * 16 + lr;
                int q = (ks * 4 + lg) ^ (br & 7);
                bv[ni] = *(const bf16x8*)((const char*)lB + br * 128 + q * 16);
            }
            #pragma unroll
            for (int mi = 0; mi < 4; ++mi)
                #pragma unroll
                for (int ni = 0; ni < 4; ++ni)
                    acc[mi][ni] = __builtin_amdgcn_mfma_f32_16x16x32_bf16(
                        av[mi], bv[ni], acc[mi][ni], 0, 0, 0);
        }
        __syncthreads();
    }
#undef OG_LOADA
#undef OG_LOADB
    const float* bp = biasb + (size_t)b * 256;
    int orow = wr * 64, ocol = n0 + wc * 64 + lr;
    #pragma unroll
    for (int mi = 0; mi < 4; ++mi) {
        int rb = orow + mi * 16 + lg * 4;
        float4 b4 = *(const float4*)&bp[rb];
        float bvr[4] = {b4.x, b4.y, b4.z, b4.w};
        #pragma unroll
        for (int ni = 0; ni < 4; ++ni) {
            int cc = ocol + ni * 16;
            #pragma unroll
            for (int r = 0; r < 4; ++r)
                out[((size_t)b * 256 + rb + r) * 4096 + cc] = acc[mi][ni][r] + bvr[r];
        }
    }
}

extern "C" void kernel_launch(void* const* d_in, const int* in_sizes, int n_in,
                              void* d_out, int out_size, void* d_ws, size_t ws_size,
                              hipStream_t stream) {
    const float* x     = (const float*)d_in[0];
    const float* cond  = (const float*)d_in[1];
    const float* gn_w  = (const float*)d_in[2];
    const float* gn_b  = (const float*)d_in[3];
    const float* w_q   = (const float*)d_in[4];
    const float* b_q   = (const float*)d_in[5];
    const float* w_kv  = (const float*)d_in[6];
    const float* b_kv  = (const float*)d_in[7];
    const float* w_out = (const float*)d_in[8];
    const float* b_out = (const float*)d_in[9];
    float* out = (float*)d_out;

    float* f       = (float*)d_ws;
    float* statacc = f;                     // 1024 floats (plain stores)
    float* rowsum  = f + 1024;              // 2048 floats (zeroed in kvprep)
    float* ctx     = f + 3072;              // 65536 floats (zeroed in kvprep)
    float* biasb   = f + 68608;             // 4096 floats
    ushort* u      = (ushort*)(f + 72704);
    ushort* kv16   = u;                     // 4194304
    ushort* A16    = u + 4194304;           // 1048576

    // L1: kv GEMM (fp32 operands, in-staging cvt) + GN stats + zeroing
    kvprep_kernel<<<1024, 256, 0, stream>>>(w_kv, cond, b_kv, kv16, x, statacc, rowsum);
    // L2: unnormalized context + row sums
    ctx_partial_kernel<<<dim3(8, 64), 256, 0, stream>>>(kv16, rowsum, ctx);
    // L3: fold everything into per-batch A (bf16) + bias
    a_kernel<<<256, 256, 0, stream>>>(ctx, rowsum, w_out, w_q, b_q, statacc,
                                      gn_w, gn_b, b_out, A16, biasb);
    // L4: out = A @ x^T + bias
    out_gemm_fused<<<dim3(32, 16), 512, 0, stream>>>(A16, x, biasb, out);
}

// Round 14
// 77.885 us; speedup vs baseline: 1.9487x; 1.0358x over previous
//
#include <hip/hip_runtime.h>
#include <hip/hip_bf16.h>

typedef __attribute__((ext_vector_type(8))) short bf16x8;
typedef __attribute__((ext_vector_type(4))) float f32x4;

__device__ __forceinline__ ushort f2bf(float f) {
    __hip_bfloat16 h = __float2bfloat16(f);
    return __builtin_bit_cast(ushort, h);
}
__device__ __forceinline__ unsigned pack2(float a, float b) {
    return (unsigned)f2bf(a) | ((unsigned)f2bf(b) << 16);
}
__device__ __forceinline__ float bflo(unsigned u) { return __uint_as_float(u << 16); }

// ---------------------------------------------------------------------------
// L1 kvctx: blocks [0,256): per (b, n-chunk of 64): kv = w_kv @ cond chunk
//   (BM=256, BN=64, BK=64, K=512, 8 waves), then IN-KERNEL epilogue:
//   bias + exp(k-half) + per-row partial sums -> rsp, bf16 tile -> LDS,
//   per-head 32x32x64 PV contraction via MFMA -> ctxp (plain stores).
//   blocks [256,768): GroupNorm sums for x, one block per (b,g).
__global__ __launch_bounds__(512) void kvctx_kernel(const float* __restrict__ w_kv,
                                                    const float* __restrict__ cond,
                                                    const float* __restrict__ b_kv,
                                                    const float* __restrict__ x,
                                                    float* __restrict__ statacc,
                                                    float* __restrict__ rsp,
                                                    float* __restrict__ ctxp) {
    __shared__ ushort lA[256 * 64];     // 32 KB (reused as bf16 kv tile in epilogue)
    __shared__ ushort lB[64 * 64];      // 8 KB
    __shared__ float scratch[64 * 64];  // 16 KB, granule-swizzled
    __shared__ float red[16];
    int bid = blockIdx.x, t = threadIdx.x;
    if (bid < 256) {
        int b = bid >> 4, nc = bid & 15;
        int col0 = nc * 64;
        int l = t & 63, w = t >> 6;          // wave 0..7, rows w*32..w*32+31
        int lr = l & 15, lg = l >> 4;
        const float* Bb = cond + (size_t)b * 512 * 1024 + col0;
        int rA = t >> 3, gAr = t & 7, gw = gAr ^ (rA & 7);  // (64m+rA)&7==rA&7
        int rB = t >> 4, gB = t & 15;
        int sp = t & 31, sj4 = t >> 5;       // k-pair (2sp,2sp+1), n-quad sj4
        float4 ka0_, ka1_, ka2_, ka3_, ka4_, ka5_, ka6_, ka7_;
        float4 kb0_, kb1_;
#define KC_LOADA(k0) { \
    ka0_ = *(const float4*)&w_kv[(size_t)(rA)       * 512 + (k0) + gAr * 8]; \
    ka1_ = *(const float4*)&w_kv[(size_t)(rA)       * 512 + (k0) + gAr * 8 + 4]; \
    ka2_ = *(const float4*)&w_kv[(size_t)(64 + rA)  * 512 + (k0) + gAr * 8]; \
    ka3_ = *(const float4*)&w_kv[(size_t)(64 + rA)  * 512 + (k0) + gAr * 8 + 4]; \
    ka4_ = *(const float4*)&w_kv[(size_t)(128 + rA) * 512 + (k0) + gAr * 8]; \
    ka5_ = *(const float4*)&w_kv[(size_t)(128 + rA) * 512 + (k0) + gAr * 8 + 4]; \
    ka6_ = *(const float4*)&w_kv[(size_t)(192 + rA) * 512 + (k0) + gAr * 8]; \
    ka7_ = *(const float4*)&w_kv[(size_t)(192 + rA) * 512 + (k0) + gAr * 8 + 4]; }
#define KC_LOADB(k0) { \
    kb0_ = *(const float4*)&Bb[(size_t)((k0) + rB)      * 1024 + gB * 4]; \
    kb1_ = *(const float4*)&Bb[(size_t)((k0) + 32 + rB) * 1024 + gB * 4]; }
#define KC_WRITEA() { uint4 p; \
    p.x = pack2(ka0_.x, ka0_.y); p.y = pack2(ka0_.z, ka0_.w); \
    p.z = pack2(ka1_.x, ka1_.y); p.w = pack2(ka1_.z, ka1_.w); \
    *(uint4*)((char*)lA + (size_t)((rA)       * 8 + gw) * 16) = p; \
    p.x = pack2(ka2_.x, ka2_.y); p.y = pack2(ka2_.z, ka2_.w); \
    p.z = pack2(ka3_.x, ka3_.y); p.w = pack2(ka3_.z, ka3_.w); \
    *(uint4*)((char*)lA + (size_t)((64 + rA)  * 8 + gw) * 16) = p; \
    p.x = pack2(ka4_.x, ka4_.y); p.y = pack2(ka4_.z, ka4_.w); \
    p.z = pack2(ka5_.x, ka5_.y); p.w = pack2(ka5_.z, ka5_.w); \
    *(uint4*)((char*)lA + (size_t)((128 + rA) * 8 + gw) * 16) = p; \
    p.x = pack2(ka6_.x, ka6_.y); p.y = pack2(ka6_.z, ka6_.w); \
    p.z = pack2(ka7_.x, ka7_.y); p.w = pack2(ka7_.z, ka7_.w); \
    *(uint4*)((char*)lA + (size_t)((192 + rA) * 8 + gw) * 16) = p; }
#define KC_WRITEB() { \
    *(float4*)((char*)scratch + (rB)      * 256 + ((gB ^ (((rB)      >> 1) & 15)) * 16)) = kb0_; \
    *(float4*)((char*)scratch + (32 + rB) * 256 + ((gB ^ (((32 + rB) >> 1) & 15)) * 16)) = kb1_; }
#define KC_PACKB() { \
    int swz = sp & 15; \
    float4 s0 = *(const float4*)((char*)scratch + (2*sp)   * 256 + ((sj4 ^ swz) * 16)); \
    float4 s2 = *(const float4*)((char*)scratch + (2*sp+1) * 256 + ((sj4 ^ swz) * 16)); \
    float c0v[4] = {s0.x, s0.y, s0.z, s0.w}; \
    float c1v[4] = {s2.x, s2.y, s2.z, s2.w}; \
    _Pragma("unroll") \
    for (int w4 = 0; w4 < 4; ++w4) { \
        int n = sj4 * 4 + w4; \
        unsigned pk = pack2(c0v[w4], c1v[w4]); \
        *(unsigned*)((char*)lB + n * 128 + (((sp >> 2) ^ (n & 7)) * 16) + (sp & 3) * 4) = pk; \
    } }
        KC_LOADA(0); KC_LOADB(0);
        f32x4 acc[2][4] = {};
        for (int it = 0; it < 8; ++it) {
            KC_WRITEA();
            KC_WRITEB();
            __syncthreads();
            if (it < 7) { KC_LOADA(it * 64 + 64); KC_LOADB(it * 64 + 64); }  // prefetch
            KC_PACKB();
            __syncthreads();
            #pragma unroll
            for (int ks = 0; ks < 2; ++ks) {
                bf16x8 av[2], bv[4];
                #pragma unroll
                for (int mi = 0; mi < 2; ++mi) {
                    int ar = w * 32 + mi * 16 + lr;
                    int q = (ks * 4 + lg) ^ (ar & 7);
                    av[mi] = *(const bf16x8*)((const char*)lA + ar * 128 + q * 16);
                }
                #pragma unroll
                for (int ni = 0; ni < 4; ++ni) {
                    int br = ni * 16 + lr;
                    int q = (ks * 4 + lg) ^ (br & 7);
                    bv[ni] = *(const bf16x8*)((const char*)lB + br * 128 + q * 16);
                }
                #pragma unroll
                for (int mi = 0; mi < 2; ++mi)
                    #pragma unroll
                    for (int ni = 0; ni < 4; ++ni)
                        acc[mi][ni] = __builtin_amdgcn_mfma_f32_16x16x32_bf16(
                            av[mi], bv[ni], acc[mi][ni], 0, 0, 0);
            }
            __syncthreads();
        }
#undef KC_LOADA
#undef KC_LOADB
#undef KC_WRITEA
#undef KC_WRITEB
#undef KC_PACKB
        // --- epilogue: bias, exp(k), rowsum partials, bf16 tile to lA ---
        bool isK = (w < 4);
        float bk[2][4];
        #pragma unroll
        for (int mi = 0; mi < 2; ++mi)
            #pragma unroll
            for (int reg = 0; reg < 4; ++reg)
                bk[mi][reg] = b_kv[w * 32 + mi * 16 + lg * 4 + reg];
        float rs[2][4];
        #pragma unroll
        for (int mi = 0; mi < 2; ++mi)
            #pragma unroll
            for (int reg = 0; reg < 4; ++reg) rs[mi][reg] = 0.f;
        #pragma unroll
        for (int mi = 0; mi < 2; ++mi) {
            #pragma unroll
            for (int ni = 0; ni < 4; ++ni) {
                #pragma unroll
                for (int reg = 0; reg < 4; ++reg) {
                    int R = w * 32 + mi * 16 + lg * 4 + reg;
                    int N = ni * 16 + lr;
                    float val = acc[mi][ni][reg] + bk[mi][reg];
                    ushort uo;
                    if (isK) {
                        uo = f2bf(__expf(val));
                        rs[mi][reg] += bflo((unsigned)uo);
                    } else {
                        uo = f2bf(val);
                    }
                    *(ushort*)((char*)lA + R * 128 + (((N >> 3) ^ (R & 7)) * 16) + (N & 7) * 2) = uo;
                }
            }
        }
        if (isK) {
            #pragma unroll
            for (int mi = 0; mi < 2; ++mi) {
                #pragma unroll
                for (int reg = 0; reg < 4; ++reg) {
                    float v = rs[mi][reg];
                    v += __shfl_xor(v, 1, 64);
                    v += __shfl_xor(v, 2, 64);
                    v += __shfl_xor(v, 4, 64);
                    v += __shfl_xor(v, 8, 64);
                    if (lr == 0)
                        rsp[(size_t)(b * 16 + nc) * 128 + w * 32 + mi * 16 + lg * 4 + reg] = v;
                }
            }
        }
        __syncthreads();
        // --- PV: per head h=w (waves 0-3): ctx[h][d][e] = sum_n expk*v via MFMA ---
        if (isK) {
            f32x4 c00 = {}, c01 = {}, c10 = {}, c11 = {};
            #pragma unroll
            for (int ks = 0; ks < 2; ++ks) {
                int ar0 = w * 32 + lr,        qa0 = (ks * 4 + lg) ^ (ar0 & 7);
                int ar1 = w * 32 + 16 + lr,   qa1 = (ks * 4 + lg) ^ (ar1 & 7);
                int br0 = 128 + w * 32 + lr,      qb0 = (ks * 4 + lg) ^ (br0 & 7);
                int br1 = 128 + w * 32 + 16 + lr, qb1 = (ks * 4 + lg) ^ (br1 & 7);
                bf16x8 pa0 = *(const bf16x8*)((const char*)lA + ar0 * 128 + qa0 * 16);
                bf16x8 pa1 = *(const bf16x8*)((const char*)lA + ar1 * 128 + qa1 * 16);
                bf16x8 pv0 = *(const bf16x8*)((const char*)lA + br0 * 128 + qb0 * 16);
                bf16x8 pv1 = *(const bf16x8*)((const char*)lA + br1 * 128 + qb1 * 16);
                c00 = __builtin_amdgcn_mfma_f32_16x16x32_bf16(pa0, pv0, c00, 0, 0, 0);
                c01 = __builtin_amdgcn_mfma_f32_16x16x32_bf16(pa0, pv1, c01, 0, 0, 0);
                c10 = __builtin_amdgcn_mfma_f32_16x16x32_bf16(pa1, pv0, c10, 0, 0, 0);
                c11 = __builtin_amdgcn_mfma_f32_16x16x32_bf16(pa1, pv1, c11, 0, 0, 0);
            }
            float* cp = ctxp + (size_t)(b * 16 + nc) * 4096 + w * 1024;
            #pragma unroll
            for (int reg = 0; reg < 4; ++reg) {
                int d0 = lg * 4 + reg;
                cp[d0 * 32 + lr]              = c00[reg];
                cp[d0 * 32 + 16 + lr]         = c01[reg];
                cp[(16 + d0) * 32 + lr]       = c10[reg];
                cp[(16 + d0) * 32 + 16 + lr]  = c11[reg];
            }
        }
    } else {
        int bg = bid - 256;              // 0..511 = (b,g)
        const float4* xp = (const float4*)(x + (size_t)bg * 32768);
        float s = 0.f, ss = 0.f;
        #pragma unroll
        for (int j = 0; j < 16; ++j) {
            float4 v = xp[t + 512 * j];
            s  += v.x + v.y + v.z + v.w;
            ss += v.x*v.x + v.y*v.y + v.z*v.z + v.w*v.w;
        }
        #pragma unroll
        for (int off = 32; off > 0; off >>= 1) {
            s  += __shfl_down(s, off, 64);
            ss += __shfl_down(ss, off, 64);
        }
        int wave = t >> 6;
        if ((t & 63) == 0) { red[wave * 2] = s; red[wave * 2 + 1] = ss; }
        __syncthreads();
        if (t == 0) {
            float S = 0.f, SS = 0.f;
            #pragma unroll
            for (int i = 0; i < 8; ++i) { S += red[i * 2]; SS += red[i * 2 + 1]; }
            statacc[bg * 2]     = S;
            statacc[bg * 2 + 1] = SS;
        }
    }
}

// ---------------------------------------------------------------------------
// L2: A-fold: sum ctx/rowsum partials, normalize, M = w_out@ctx^T in LDS, then
// A16[b,o,c] = bf16(wt*s), biasb[b,o] = sum_c wt*t + M.b_q + b_out
__global__ __launch_bounds__(256) void a_kernel(const float* __restrict__ ctxp,
                                                const float* __restrict__ rsp,
                                                const float* __restrict__ w_out,
                                                const float* __restrict__ w_q,
                                                const float* __restrict__ b_q,
                                                const float* __restrict__ statacc,
                                                const float* __restrict__ gn_w,
                                                const float* __restrict__ gn_b,
                                                const float* __restrict__ b_out,
                                                ushort* __restrict__ A16,
                                                float* __restrict__ biasb) {
    __shared__ float ctxl[4][32][33];
    __shared__ float wol[16][128];
    __shared__ float ml[16][128];
    __shared__ float cbuf[256][17];
    __shared__ float pbuf[16][17];
    __shared__ float rsinv[128];
    int b = blockIdx.x >> 4, ot = (blockIdx.x & 15) << 4;
    int t = threadIdx.x;
    if (t < 128) {
        float s = 0.f;
        #pragma unroll
        for (int nc = 0; nc < 16; ++nc)
            s += rsp[(size_t)(b * 16 + nc) * 128 + t];
        rsinv[t] = 1.f / s;
    }
    #pragma unroll
    for (int j = 0; j < 8; ++j) {
        int e = t + 256 * j;            // 0..2047
        wol[e >> 7][e & 127] = w_out[(ot + (e >> 7)) * 128 + (e & 127)];
    }
    __syncthreads();
    #pragma unroll
    for (int j = 0; j < 16; ++j) {
        int e = t + 256 * j;            // 0..4095
        float v = 0.f;
        #pragma unroll
        for (int nc = 0; nc < 16; ++nc)
            v += ctxp[(size_t)(b * 16 + nc) * 4096 + e];
        ctxl[e >> 10][(e >> 5) & 31][e & 31] = v * rsinv[e >> 5];
    }
    __syncthreads();
    #pragma unroll
    for (int j = 0; j < 8; ++j) {
        int e = t + 256 * j;
        int o = e >> 7, hd = e & 127, h = hd >> 5, d = hd & 31;
        float acc = 0.f;
        #pragma unroll
        for (int ee = 0; ee < 32; ++ee) acc += wol[o][h * 32 + ee] * ctxl[h][d][ee];
        ml[o][hd] = acc;
    }
    __syncthreads();
    int c = t, g = c >> 3;
    float a0 = statacc[(b * 32 + g) * 2], a1 = statacc[(b * 32 + g) * 2 + 1];
    float mu  = a0 * (1.f / 32768.f);
    float var = a1 * (1.f / 32768.f) - mu * mu;
    float sc = rsqrtf(var + 1e-5f) * gn_w[c];
    float tc = gn_b[c] - mu * sc;
    float wt[16];
    #pragma unroll
    for (int o = 0; o < 16; ++o) wt[o] = 0.f;
    for (int hd = 0; hd < 128; ++hd) {
        float wq = w_q[hd * 256 + c];
        #pragma unroll
        for (int o = 0; o < 16; ++o) wt[o] += ml[o][hd] * wq;
    }
    ushort* Abp = A16 + ((size_t)b * 256 + ot) * 256 + c;
    #pragma unroll
    for (int o = 0; o < 16; ++o) {
        Abp[(size_t)o * 256] = f2bf(wt[o] * sc);
        cbuf[c][o] = wt[o] * tc;
    }
    __syncthreads();
    {
        int o = t >> 4, seg = t & 15;
        float p = 0.f;
        #pragma unroll
        for (int i = 0; i < 16; ++i) p += cbuf[seg * 16 + i][o];
        pbuf[o][seg] = p;
    }
    __syncthreads();
    if (t < 16) {
        int o = t;
        float sum = 0.f;
        #pragma unroll
        for (int s2 = 0; s2 < 16; ++s2) sum += pbuf[o][s2];
        float md = 0.f;
        #pragma unroll 8
        for (int hd = 0; hd < 128; ++hd) md += ml[o][hd] * b_q[hd];
        biasb[(size_t)b * 256 + ot + o] = sum + md + b_out[ot + o];
    }
}

// ---------------------------------------------------------------------------
// L3: out = A16 @ x^T + bias.  BM=256, BN=128, BK=64; 8 waves (4x2), 512 thr.
// A and B reg-staged via NAMED regs with next-tile prefetch.
__global__ __launch_bounds__(512) void out_gemm_fused(const ushort* __restrict__ A16,
                                                      const float* __restrict__ x,
                                                      const float* __restrict__ biasb,
                                                      float* __restrict__ out) {
    __shared__ ushort lA[256 * 64];     // 32 KB
    __shared__ ushort lB[128 * 64];     // 16 KB
    __shared__ float scratch[64 * 128]; // 32 KB, granule-swizzled
    int b = blockIdx.y;
    int n0 = blockIdx.x * 128;
    int t = threadIdx.x;
    int l = t & 63, wid = t >> 6;
    int wr = wid >> 1, wc = wid & 1;          // 4 x 2 wave grid
    int lr = l & 15, lg = l >> 4;
    const ushort* Ab = A16 + (size_t)b * 65536;
    const float* xb = x + (size_t)b * 256 * 4096 + n0;
    int sp = t & 31, sj = t >> 5;             // c-pair (2sp,2sp+1), n-octet (16)
    uint4 a0_, a1_, a2_, a3_;
    float4 b0_, b1_, b2_, b3_;
    int rA = t >> 3, gA = (t & 7) ^ (rA & 7); // (64k+rA)&7 == rA&7
    int rB = t >> 5, gB = t & 31;
#define OG_LOADA(k0) { \
    a0_ = *(const uint4*)(Ab + (size_t)(rA)       * 256 + (k0) + gA * 8); \
    a1_ = *(const uint4*)(Ab + (size_t)(64 + rA)  * 256 + (k0) + gA * 8); \
    a2_ = *(const uint4*)(Ab + (size_t)(128 + rA) * 256 + (k0) + gA * 8); \
    a3_ = *(const uint4*)(Ab + (size_t)(192 + rA) * 256 + (k0) + gA * 8); }
#define OG_LOADB(k0) { \
    b0_ = *(const float4*)&xb[(size_t)((k0) + rB)      * 4096 + gB * 4]; \
    b1_ = *(const float4*)&xb[(size_t)((k0) + 16 + rB) * 4096 + gB * 4]; \
    b2_ = *(const float4*)&xb[(size_t)((k0) + 32 + rB) * 4096 + gB * 4]; \
    b3_ = *(const float4*)&xb[(size_t)((k0) + 48 + rB) * 4096 + gB * 4]; }
    OG_LOADA(0); OG_LOADB(0);
    f32x4 acc[4][4] = {};
    for (int it = 0; it < 4; ++it) {
        *(uint4*)((char*)lA + (size_t)t * 16)          = a0_;
        *(uint4*)((char*)lA + (size_t)(512 + t) * 16)  = a1_;
        *(uint4*)((char*)lA + (size_t)(1024 + t) * 16) = a2_;
        *(uint4*)((char*)lA + (size_t)(1536 + t) * 16) = a3_;
        *(float4*)((char*)scratch + (rB)      * 512 + (gB ^ (((rB)      >> 1) & 31)) * 16) = b0_;
        *(float4*)((char*)scratch + (16 + rB) * 512 + (gB ^ (((16 + rB) >> 1) & 31)) * 16) = b1_;
        *(float4*)((char*)scratch + (32 + rB) * 512 + (gB ^ (((32 + rB) >> 1) & 31)) * 16) = b2_;
        *(float4*)((char*)scratch + (48 + rB) * 512 + (gB ^ (((48 + rB) >> 1) & 31)) * 16) = b3_;
        __syncthreads();
        if (it < 3) { OG_LOADA(it * 64 + 64); OG_LOADB(it * 64 + 64); }   // prefetch
        {
            int swz = sp & 31;
            float4 s0 = *(const float4*)((char*)scratch + (2*sp)   * 512 + ((2*sj)   ^ swz) * 16);
            float4 s1 = *(const float4*)((char*)scratch + (2*sp)   * 512 + ((2*sj+1) ^ swz) * 16);
            float4 s2 = *(const float4*)((char*)scratch + (2*sp+1) * 512 + ((2*sj)   ^ swz) * 16);
            float4 s3 = *(const float4*)((char*)scratch + (2*sp+1) * 512 + ((2*sj+1) ^ swz) * 16);
            float c0v[8] = {s0.x, s0.y, s0.z, s0.w, s1.x, s1.y, s1.z, s1.w};
            float c1v[8] = {s2.x, s2.y, s2.z, s2.w, s3.x, s3.y, s3.z, s3.w};
            #pragma unroll
            for (int w = 0; w < 8; ++w) {
                int n = sj * 8 + w;
                unsigned pk = pack2(c0v[w], c1v[w]);
                *(unsigned*)((char*)lB + n * 128 + (((sp >> 2) ^ (n & 7)) * 16) + (sp & 3) * 4) = pk;
            }
        }
        __syncthreads();
        #pragma unroll
        for (int ks = 0; ks < 2; ++ks) {
            bf16x8 av[4], bv[4];
            #pragma unroll
            for (int mi = 0; mi < 4; ++mi) {
                int ar = wr * 64 + mi * 16 + lr;
                int q = (ks * 4 + lg) ^ (ar & 7);
                av[mi] = *(const bf16x8*)((const char*)lA + ar * 128 + q * 16);
            }
            #pragma unroll
            for (int ni = 0; ni < 4; ++ni) {
                int br = wc * 64 + ni * 16 + lr;
                int q = (ks * 4 + lg) ^ (br & 7);
                bv[ni] = *(const bf16x8*)((const char*)lB + br * 128 + q * 16);
            }
            #pragma unroll
            for (int mi = 0; mi < 4; ++mi)
                #pragma unroll
                for (int ni = 0; ni < 4; ++ni)
                    acc[mi][ni] = __builtin_amdgcn_mfma_f32_16x16x32_bf16(
                        av[mi], bv[ni], acc[mi][ni], 0, 0, 0);
        }
        __syncthreads();
    }
#undef OG_LOADA
#undef OG_LOADB
    const float* bp = biasb + (size_t)b * 256;
    int orow = wr * 64, ocol = n0 + wc * 64 + lr;
    #pragma unroll
    for (int mi = 0; mi < 4; ++mi) {
        int rb = orow + mi * 16 + lg * 4;
        float4 b4 = *(const float4*)&bp[rb];
        float bvr[4] = {b4.x, b4.y, b4.z, b4.w};
        #pragma unroll
        for (int ni = 0; ni < 4; ++ni) {
            int cc = ocol + ni * 16;
            #pragma unroll
            for (int r = 0; r < 4; ++r)
                out[((size_t)b * 256 + rb + r) * 4096 + cc] = acc[mi][ni][r] + bvr[r];
        }
    }
}

extern "C" void kernel_launch(void* const* d_in, const int* in_sizes, int n_in,
                              void* d_out, int out_size, void* d_ws, size_t ws_size,
                              hipStream_t stream) {
    const float* x     = (const float*)d_in[0];
    const float* cond  = (const float*)d_in[1];
    const float* gn_w  = (const float*)d_in[2];
    const float* gn_b  = (const float*)d_in[3];
    const float* w_q   = (const float*)d_in[4];
    const float* b_q   = (const float*)d_in[5];
    const float* w_kv  = (const float*)d_in[6];
    const float* b_kv  = (const float*)d_in[7];
    const float* w_out = (const float*)d_in[8];
    const float* b_out = (const float*)d_in[9];
    float* out = (float*)d_out;

    float* f       = (float*)d_ws;
    float* statacc = f;                     // 1024 floats (plain stores)
    float* rsp     = f + 1024;              // 16*16*128 = 32768 floats (plain stores)
    float* ctxp    = f + 33792;             // 16*16*4096 = 1048576 floats (plain stores)
    float* biasb   = f + 1082368;           // 4096 floats
    ushort* A16    = (ushort*)(f + 1086464);// 1048576 ushorts

    // L1: kv GEMM + fused exp/PV context partials + GN stats (one dispatch)
    kvctx_kernel<<<768, 512, 0, stream>>>(w_kv, cond, b_kv, x, statacc, rsp, ctxp);
    // L2: fold everything into per-batch A (bf16) + bias
    a_kernel<<<256, 256, 0, stream>>>(ctxp, rsp, w_out, w_q, b_q, statacc,
                                      gn_w, gn_b, b_out, A16, biasb);
    // L3: out = A @ x^T + bias
    out_gemm_fused<<<dim3(32, 16), 512, 0, stream>>>(A16, x, biasb, out);
}